// Round 3
// baseline (334.235 us; speedup 1.0000x reference)
//
#include <hip/hip_runtime.h>
#include <hip/hip_fp16.h>

#define TEMP 10.0f
#define TPB 512           // scatter block size
#define HTPB 256          // hist block size
#define NBLK 784          // hist/scatter grid -> span 4082 = exactly 2 tiles
#define SHIFT 9
#define GSZ 512           // nodes per bucket = 1<<SHIFT
#define BMAX 256          // max buckets (fits b in 16 spare bits of pk.w)
#define TILE 2048         // edges per scatter tile
#define GTPB 1024         // gather block size (one block per bucket)

typedef float v2f  __attribute__((ext_vector_type(2)));
typedef float vf4  __attribute__((ext_vector_type(4)));
typedef unsigned uv4 __attribute__((ext_vector_type(4)));

__device__ __forceinline__ int   nt_i (const int* p)   { return __builtin_nontemporal_load(p); }
__device__ __forceinline__ float nt_f (const float* p) { return __builtin_nontemporal_load(p); }
__device__ __forceinline__ float4 nt_f4(const float4* p) {
    vf4 v = __builtin_nontemporal_load((const vf4*)p);
    return make_float4(v.x, v.y, v.z, v.w);
}
__device__ __forceinline__ uint4 nt_u4(const uint4* p) {
    uv4 v = __builtin_nontemporal_load((const uv4*)p);
    uint4 r; r.x = v.x; r.y = v.y; r.z = v.z; r.w = v.w; return r;
}

__device__ __forceinline__ void pk_fadd(float* p, float a, float b) {
#if __has_builtin(__builtin_amdgcn_global_atomic_fadd_v2f32)
    v2f v; v.x = a; v.y = b;
    __builtin_amdgcn_global_atomic_fadd_v2f32(
        (__attribute__((address_space(1))) v2f*)p, v);
#else
    atomicAdd(p, a); atomicAdd(p + 1, b);
#endif
}

// native LDS f32 add (HIP's atomicAdd(float*) on shared is a CAS loop by default)
__device__ __forceinline__ void lds_fadd(float* p, float v) {
#if __has_builtin(__builtin_amdgcn_ds_faddf)
    __builtin_amdgcn_ds_faddf((__attribute__((address_space(3))) float*)p, v, 0, 0, false);
#else
    atomicAdd(p, v);
#endif
}

__device__ __forceinline__ void hamilton(float4 a, float4 b,
                                         float& ow, float& ox, float& oy, float& oz) {
    ow = a.x*b.x - a.y*b.y - a.z*b.z - a.w*b.w;
    ox = a.x*b.y + a.y*b.x + a.z*b.w - a.w*b.z;
    oy = a.x*b.z - a.y*b.w + a.z*b.x + a.w*b.y;
    oz = a.x*b.w + a.y*b.z - a.z*b.y + a.w*b.x;
}

__device__ __forceinline__ unsigned f2h(float x) {
    return (unsigned)__half_as_ushort(__float2half_rn(x));
}
__device__ __forceinline__ float h2f(unsigned u) {
    return __half2float(__ushort_as_half((unsigned short)(u & 0xFFFFu)));
}

// ---------- pass H: per-block LDS histogram of dst buckets ----------
__global__ void __launch_bounds__(HTPB)
hist_kernel(const int* __restrict__ dst, unsigned* __restrict__ blkhist,
            int E, int B, int span) {
    extern __shared__ unsigned h[];
    for (int i = threadIdx.x; i < B; i += blockDim.x) h[i] = 0;
    __syncthreads();
    int start = blockIdx.x * span;
    int end = start + span; if (end > E) end = E;
    for (int e = start + threadIdx.x; e < end; e += blockDim.x)
        atomicAdd(&h[((unsigned)nt_i(&dst[e])) >> SHIFT], 1u);
    __syncthreads();
    for (int i = threadIdx.x; i < B; i += blockDim.x)
        blkhist[(size_t)i * gridDim.x + blockIdx.x] = h[i];  // bucket-major
}

// ---------- pass P1: exclusive scan across blocks, per bucket ----------
__global__ void __launch_bounds__(1024)
scan_blocks_kernel(unsigned* __restrict__ blkhist, unsigned* __restrict__ totals) {
    __shared__ unsigned s[1024];
    int b = blockIdx.x, t = threadIdx.x, n = blockDim.x;
    unsigned v = blkhist[(size_t)b * n + t];
    s[t] = v; __syncthreads();
    for (int off = 1; off < n; off <<= 1) {
        unsigned add = (t >= off) ? s[t - off] : 0u;
        __syncthreads();
        s[t] += add;
        __syncthreads();
    }
    blkhist[(size_t)b * n + t] = s[t] - v;   // exclusive (local base)
    if (t == n - 1) totals[b] = s[t];
}

// ---------- pass P2: exclusive scan of bucket totals ----------
__global__ void __launch_bounds__(1024)
scan_totals_kernel(const unsigned* __restrict__ totals,
                   unsigned* __restrict__ offsets, int B) {
    __shared__ unsigned s[1024];
    int t = threadIdx.x;
    unsigned v = (t < B) ? totals[t] : 0u;
    s[t] = v; __syncthreads();
    for (int off = 1; off < 1024; off <<= 1) {
        unsigned add = (t >= off) ? s[t - off] : 0u;
        __syncthreads();
        s[t] += add;
        __syncthreads();
    }
    if (t < B) offsets[t] = s[t] - v;
    if (t == B - 1) offsets[B] = s[t];
}

// ---------- pass S: tile-sorted payload placement (no global atomics) ----------
// Bucket id rides in the high 16 bits of pk.w (gather decodes h2f(low16) only),
// so no gslot[] array is needed: flush recomputes slot = gcur[b] + (k - basec[b]).
__global__ void __launch_bounds__(TPB)
scatter_sort_kernel(const float* __restrict__ nl, const float4* __restrict__ nq,
                    const float4* __restrict__ erq, const float* __restrict__ ew,
                    const int* __restrict__ src, const int* __restrict__ dst,
                    const unsigned* __restrict__ blkhist,
                    const unsigned* __restrict__ offsets,
                    uint4* __restrict__ buckets,
                    int E, int B, int span) {
    __shared__ uint4    stage[TILE];     // 32 KB
    __shared__ unsigned gcur[BMAX];      //  1 KB each below
    __shared__ unsigned th[BMAX];
    __shared__ unsigned basec[BMAX];
    __shared__ unsigned curt[BMAX];

    int blk = blockIdx.x, nb = gridDim.x, tid = threadIdx.x;
    for (int b = tid; b < B; b += TPB)
        gcur[b] = offsets[b] + blkhist[(size_t)b * nb + blk];
    int start = blk * span;
    int end = start + span; if (end > E) end = E;

    for (int ts = start; ts < end; ts += TILE) {
        int tE = end - ts; if (tE > TILE) tE = TILE;
        for (int b = tid; b < B; b += TPB) th[b] = 0;
        __syncthreads();
        // tile histogram
        for (int k = tid; k < tE; k += TPB)
            atomicAdd(&th[((unsigned)dst[ts + k]) >> SHIFT], 1u);
        __syncthreads();
        // single-wave exclusive scan over B buckets (B <= BMAX = 64*4)
        if (tid < 64) {
            int lane = tid;
            unsigned vals[4];
            unsigned tot = 0;
            #pragma unroll
            for (int c = 0; c < 4; ++c) {
                int i = lane * 4 + c;
                vals[c] = (i < B) ? th[i] : 0u;
                tot += vals[c];
            }
            unsigned inc = tot;
            #pragma unroll
            for (int off = 1; off < 64; off <<= 1) {
                unsigned up = __shfl_up(inc, off);
                if (lane >= off) inc += up;
            }
            unsigned run = inc - tot;     // exclusive
            #pragma unroll
            for (int c = 0; c < 4; ++c) {
                int i = lane * 4 + c;
                if (i < B) { basec[i] = run; curt[i] = run; }
                run += vals[c];
            }
        }
        __syncthreads();
        // compute payloads, place bucket-sorted into LDS stage
        for (int k = tid; k < tE; k += TPB) {
            int e = ts + k;
            int s_ = nt_i(&src[e]);
            unsigned d = (unsigned)dst[e];
            float l = nl[s_];
            float p = __expf(TEMP * nt_f(&ew[e]) * l);
            float ow, ox, oy, oz;
            hamilton(nt_f4(&erq[e]), nq[s_], ow, ox, oy, oz);
            unsigned b = d >> SHIFT;
            unsigned pos = atomicAdd(&curt[b], 1u);
            uint4 pk;
            pk.x = (d & (GSZ - 1)) | (f2h(p) << 16);
            pk.y = f2h(p * l)  | (f2h(p * ow) << 16);
            pk.z = f2h(p * ox) | (f2h(p * oy) << 16);
            pk.w = f2h(p * oz) | (b << 16);          // bucket id in spare bits
            stage[pos] = pk;
        }
        __syncthreads();
        // flush in sorted order: consecutive lanes -> consecutive slots
        for (int k = tid; k < tE; k += TPB) {
            uint4 pk = stage[k];
            unsigned b = pk.w >> 16;
            buckets[gcur[b] + ((unsigned)k - basec[b])] = pk;
        }
        __syncthreads();
        for (int b = tid; b < B; b += TPB) gcur[b] += th[b];
        __syncthreads();
    }
}

// ---------- pass G: one block per bucket, native ds_add_f32, fused finalize ----------
// Block exclusively owns its GSZ nodes: LDS accumulator IS the final edge sum,
// flushed with plain coalesced stores. No global atomics anywhere.
__global__ void __launch_bounds__(GTPB)
gather_fused_kernel(const float* __restrict__ nl, const float4* __restrict__ nq,
                    const unsigned* __restrict__ offsets,
                    const uint4* __restrict__ buckets,
                    float4* __restrict__ out_q, float* __restrict__ out_l, int N) {
    __shared__ float acc[GSZ * 7];              // stride 7 -> conflict-light
    int b = blockIdx.x, tid = threadIdx.x;
    for (int i = tid; i < GSZ * 7; i += GTPB) acc[i] = 0.f;
    __syncthreads();

    unsigned s0 = offsets[b], s1 = offsets[b + 1];
    int M = (int)(s1 - s0);

    for (int i = tid; i < M; i += GTPB) {
        uint4 pk = nt_u4(&buckets[s0 + i]);
        float* a = &acc[(pk.x & (GSZ - 1)) * 7];
        lds_fadd(a + 0, h2f(pk.x >> 16));
        lds_fadd(a + 1, h2f(pk.y));
        lds_fadd(a + 2, h2f(pk.y >> 16));
        lds_fadd(a + 3, h2f(pk.z));
        lds_fadd(a + 4, h2f(pk.z >> 16));
        lds_fadd(a + 5, h2f(pk.w));
    }
    __syncthreads();

    int j = tid;                                 // thread j owns node j (j < GSZ)
    int n = b * GSZ + j;
    if (j < GSZ && n < N) {
        const float* a = &acc[j * 7];
        float l  = nl[n];
        float ps = __expf(TEMP * l);
        float Z  = a[0] + ps;
        float sl = a[1] + ps * l;
        float4 q = nq[n];
        float qw = a[2] + ps * q.x;
        float qx = a[3] + ps * q.y;
        float qy = a[4] + ps * q.z;
        float qz = a[5] + ps * q.w;
        float inv = 1.0f / Z;
        qw *= inv; qx *= inv; qy *= inv; qz *= inv;
        float norm = fmaxf(sqrtf(qw*qw + qx*qx + qy*qy + qz*qz), 1e-12f);
        float rn = 1.0f / norm;
        out_q[n] = make_float4(qw * rn, qx * rn, qy * rn, qz * rn);
        out_l[n] = sl * inv;
    }
}

// ---------------- fallback path (R3) ----------------
__global__ void __launch_bounds__(256)
scatter_kernel(const int* __restrict__ dst, int* __restrict__ cnt,
               int* __restrict__ bucket, int cap,
               const float* __restrict__ node_levels, const float4* __restrict__ node_q,
               const float4* __restrict__ edge_rel_q, const float* __restrict__ edge_w,
               const int* __restrict__ src, float* __restrict__ side, int E) {
    int e = blockIdx.x * blockDim.x + threadIdx.x;
    if (e >= E) return;
    int d = dst[e];
    int slot = atomicAdd(&cnt[d], 1);
    if (slot < cap) {
        bucket[(long long)d * cap + slot] = e;
    } else {
        int s = src[e];
        float l = node_levels[s];
        float p = __expf(TEMP * edge_w[e] * l);
        float ow, ox, oy, oz;
        hamilton(edge_rel_q[e], node_q[s], ow, ox, oy, oz);
        float* rec = side + 6 * (long long)d;
        pk_fadd(rec + 0, p,      p * l);
        pk_fadd(rec + 2, p * ow, p * ox);
        pk_fadd(rec + 4, p * oy, p * oz);
    }
}

__global__ void __launch_bounds__(256)
gather_kernel(const float* __restrict__ node_levels, const float4* __restrict__ node_q,
              const float4* __restrict__ edge_rel_q, const float* __restrict__ edge_w,
              const int* __restrict__ src, const int* __restrict__ cnt,
              const int* __restrict__ bucket, int cap, const float* __restrict__ side,
              float4* __restrict__ out_q, float* __restrict__ out_l, int N) {
    int tid  = blockIdx.x * blockDim.x + threadIdx.x;
    int wave = tid >> 6, lane = tid & 63, half = lane >> 5, sub = lane & 31;
    int n = wave * 2 + half;
    float aZ = 0.f, aL = 0.f, a0 = 0.f, a1 = 0.f, a2 = 0.f, a3 = 0.f;
    if (n < N) {
        int deg = cnt[n]; if (deg > cap) deg = cap;
        const int* bkt = bucket + (long long)n * cap;
        for (int s = sub; s < deg; s += 32) {
            int e = bkt[s];
            int sn = src[e];
            float l = node_levels[sn];
            float p = __expf(TEMP * edge_w[e] * l);
            float ow, ox, oy, oz;
            hamilton(edge_rel_q[e], node_q[sn], ow, ox, oy, oz);
            aZ += p; aL += p * l; a0 += p * ow; a1 += p * ox; a2 += p * oy; a3 += p * oz;
        }
    }
    for (int m = 16; m; m >>= 1) {
        aZ += __shfl_xor(aZ, m); aL += __shfl_xor(aL, m);
        a0 += __shfl_xor(a0, m); a1 += __shfl_xor(a1, m);
        a2 += __shfl_xor(a2, m); a3 += __shfl_xor(a3, m);
    }
    if (sub == 0 && n < N) {
        const float* rec = side + 6 * (long long)n;
        float l  = node_levels[n];
        float ps = __expf(TEMP * l);
        float Z  = aZ + rec[0] + ps;
        float sl = aL + rec[1] + ps * l;
        float4 q = node_q[n];
        float qw = a0 + rec[2] + ps * q.x;
        float qx = a1 + rec[3] + ps * q.y;
        float qy = a2 + rec[4] + ps * q.z;
        float qz = a3 + rec[5] + ps * q.w;
        float inv = 1.0f / Z;
        qw *= inv; qx *= inv; qy *= inv; qz *= inv;
        float norm = fmaxf(sqrtf(qw*qw + qx*qx + qy*qy + qz*qz), 1e-12f);
        float rn = 1.0f / norm;
        out_q[n] = make_float4(qw * rn, qx * rn, qy * rn, qz * rn);
        out_l[n] = sl * inv;
    }
}

extern "C" void kernel_launch(void* const* d_in, const int* in_sizes, int n_in,
                              void* d_out, int out_size, void* d_ws, size_t ws_size,
                              hipStream_t stream) {
    const float*  node_levels = (const float*)d_in[0];
    const float4* node_q      = (const float4*)d_in[1];
    const float4* edge_rel_q  = (const float4*)d_in[2];
    const float*  edge_w      = (const float*)d_in[3];
    const int*    src         = (const int*)d_in[4];
    const int*    dst         = (const int*)d_in[5];

    const int N = in_sizes[0];
    const int E = in_sizes[3];

    const int B = (N + GSZ - 1) / GSZ;            // coarse buckets
    const int span = (E + NBLK - 1) / NBLK;

    // ws layout: blkhist[B*NBLK] u32 | totals[B] | offsets[B+1] | pad | buckets[E] uint4
    size_t head_elems   = (size_t)B * NBLK + B + (B + 1);
    size_t buckets_byte = (head_elems * 4 + 15) & ~(size_t)15;
    size_t need         = buckets_byte + (size_t)E * 16;

    if (need <= ws_size && B <= BMAX) {
        unsigned* blkhist = (unsigned*)d_ws;
        unsigned* totals  = blkhist + (size_t)B * NBLK;
        unsigned* offsets = totals + B;
        uint4*    buckets = (uint4*)((char*)d_ws + buckets_byte);

        hist_kernel<<<NBLK, HTPB, B * 4, stream>>>(dst, blkhist, E, B, span);
        scan_blocks_kernel<<<B, NBLK, 0, stream>>>(blkhist, totals);
        scan_totals_kernel<<<1, 1024, 0, stream>>>(totals, offsets, B);
        scatter_sort_kernel<<<NBLK, TPB, 0, stream>>>(
            node_levels, node_q, edge_rel_q, edge_w, src, dst,
            blkhist, offsets, buckets, E, B, span);
        gather_fused_kernel<<<B, GTPB, 0, stream>>>(
            node_levels, node_q, offsets, buckets,
            (float4*)d_out, (float*)d_out + 4 * (long long)N, N);
    } else {
        // R3 fallback
        const int tpb = 256;
        size_t cnt_elems  = ((size_t)N + 3) & ~(size_t)3;
        size_t side_elems = 6 * (size_t)N;
        size_t head_bytes = (cnt_elems + side_elems) * 4;
        int cap = 0;
        for (int c : {128, 64}) {
            if (head_bytes + (size_t)N * c * 4 <= ws_size) { cap = c; break; }
        }
        int*   cnt    = (int*)d_ws;
        float* side   = (float*)d_ws + cnt_elems;
        int*   bucket = (int*)d_ws + cnt_elems + side_elems;
        hipMemsetAsync(d_ws, 0, head_bytes, stream);
        scatter_kernel<<<(E + tpb - 1) / tpb, tpb, 0, stream>>>(
            dst, cnt, bucket, cap, node_levels, node_q, edge_rel_q, edge_w, src, side, E);
        int waves  = (N + 1) / 2;
        int blocks = (waves * 64 + tpb - 1) / tpb;
        gather_kernel<<<blocks, tpb, 0, stream>>>(
            node_levels, node_q, edge_rel_q, edge_w, src, cnt, bucket, cap, side,
            (float4*)d_out, (float*)d_out + 4 * (long long)N, N);
    }
}

// Round 4
// 228.578 us; speedup vs baseline: 1.4622x; 1.4622x over previous
//
#include <hip/hip_runtime.h>
#include <hip/hip_fp16.h>

#define TEMP 10.0f
#define TPB 512           // scatter block size
#define HTPB 256          // hist block size
#define NBLK 784          // hist/scatter grid -> span 4082 = exactly 2 tiles
#define SHIFT 9
#define GSZ 512           // nodes per bucket = 1<<SHIFT
#define BMAX 256          // max buckets (fits b in 16 spare bits of pk.w)
#define TILE 2048         // edges per scatter tile
#define GTPB 1024         // gather block size
#define GT 4096           // records per gather tile (4 regs/thread)

typedef float v2f  __attribute__((ext_vector_type(2)));
typedef float vf4  __attribute__((ext_vector_type(4)));
typedef unsigned uv4 __attribute__((ext_vector_type(4)));

__device__ __forceinline__ int   nt_i (const int* p)   { return __builtin_nontemporal_load(p); }
__device__ __forceinline__ float nt_f (const float* p) { return __builtin_nontemporal_load(p); }
__device__ __forceinline__ float4 nt_f4(const float4* p) {
    vf4 v = __builtin_nontemporal_load((const vf4*)p);
    return make_float4(v.x, v.y, v.z, v.w);
}
__device__ __forceinline__ uint4 nt_u4(const uint4* p) {
    uv4 v = __builtin_nontemporal_load((const uv4*)p);
    uint4 r; r.x = v.x; r.y = v.y; r.z = v.z; r.w = v.w; return r;
}

__device__ __forceinline__ void pk_fadd(float* p, float a, float b) {
#if __has_builtin(__builtin_amdgcn_global_atomic_fadd_v2f32)
    v2f v; v.x = a; v.y = b;
    __builtin_amdgcn_global_atomic_fadd_v2f32(
        (__attribute__((address_space(1))) v2f*)p, v);
#else
    atomicAdd(p, a); atomicAdd(p + 1, b);
#endif
}

__device__ __forceinline__ void hamilton(float4 a, float4 b,
                                         float& ow, float& ox, float& oy, float& oz) {
    ow = a.x*b.x - a.y*b.y - a.z*b.z - a.w*b.w;
    ox = a.x*b.y + a.y*b.x + a.z*b.w - a.w*b.z;
    oy = a.x*b.z - a.y*b.w + a.z*b.x + a.w*b.y;
    oz = a.x*b.w + a.y*b.z - a.z*b.y + a.w*b.x;
}

__device__ __forceinline__ unsigned f2h(float x) {
    return (unsigned)__half_as_ushort(__float2half_rn(x));
}
__device__ __forceinline__ float h2f(unsigned u) {
    return __half2float(__ushort_as_half((unsigned short)(u & 0xFFFFu)));
}

// ---------- pass H: per-block LDS histogram of dst buckets ----------
__global__ void __launch_bounds__(HTPB)
hist_kernel(const int* __restrict__ dst, unsigned* __restrict__ blkhist,
            int E, int B, int span) {
    extern __shared__ unsigned h[];
    for (int i = threadIdx.x; i < B; i += blockDim.x) h[i] = 0;
    __syncthreads();
    int start = blockIdx.x * span;
    int end = start + span; if (end > E) end = E;
    for (int e = start + threadIdx.x; e < end; e += blockDim.x)
        atomicAdd(&h[((unsigned)nt_i(&dst[e])) >> SHIFT], 1u);
    __syncthreads();
    for (int i = threadIdx.x; i < B; i += blockDim.x)
        blkhist[(size_t)i * gridDim.x + blockIdx.x] = h[i];  // bucket-major
}

// ---------- pass P1: exclusive scan across blocks, per bucket ----------
__global__ void __launch_bounds__(1024)
scan_blocks_kernel(unsigned* __restrict__ blkhist, unsigned* __restrict__ totals) {
    __shared__ unsigned s[1024];
    int b = blockIdx.x, t = threadIdx.x, n = blockDim.x;
    unsigned v = blkhist[(size_t)b * n + t];
    s[t] = v; __syncthreads();
    for (int off = 1; off < n; off <<= 1) {
        unsigned add = (t >= off) ? s[t - off] : 0u;
        __syncthreads();
        s[t] += add;
        __syncthreads();
    }
    blkhist[(size_t)b * n + t] = s[t] - v;   // exclusive (local base)
    if (t == n - 1) totals[b] = s[t];
}

// ---------- pass P2: exclusive scan of bucket totals ----------
__global__ void __launch_bounds__(1024)
scan_totals_kernel(const unsigned* __restrict__ totals,
                   unsigned* __restrict__ offsets, int B) {
    __shared__ unsigned s[1024];
    int t = threadIdx.x;
    unsigned v = (t < B) ? totals[t] : 0u;
    s[t] = v; __syncthreads();
    for (int off = 1; off < 1024; off <<= 1) {
        unsigned add = (t >= off) ? s[t - off] : 0u;
        __syncthreads();
        s[t] += add;
        __syncthreads();
    }
    if (t < B) offsets[t] = s[t] - v;
    if (t == B - 1) offsets[B] = s[t];
}

// ---------- pass S: tile-sorted payload placement (no global atomics) ----------
// Bucket id rides in the high 16 bits of pk.w (gather decodes h2f(low16) only),
// so no gslot[] array is needed: flush recomputes slot = gcur[b] + (k - basec[b]).
__global__ void __launch_bounds__(TPB)
scatter_sort_kernel(const float* __restrict__ nl, const float4* __restrict__ nq,
                    const float4* __restrict__ erq, const float* __restrict__ ew,
                    const int* __restrict__ src, const int* __restrict__ dst,
                    const unsigned* __restrict__ blkhist,
                    const unsigned* __restrict__ offsets,
                    uint4* __restrict__ buckets,
                    int E, int B, int span) {
    __shared__ uint4    stage[TILE];     // 32 KB
    __shared__ unsigned gcur[BMAX];      //  1 KB each below
    __shared__ unsigned th[BMAX];
    __shared__ unsigned basec[BMAX];
    __shared__ unsigned curt[BMAX];

    int blk = blockIdx.x, nb = gridDim.x, tid = threadIdx.x;
    for (int b = tid; b < B; b += TPB)
        gcur[b] = offsets[b] + blkhist[(size_t)b * nb + blk];
    int start = blk * span;
    int end = start + span; if (end > E) end = E;

    for (int ts = start; ts < end; ts += TILE) {
        int tE = end - ts; if (tE > TILE) tE = TILE;
        for (int b = tid; b < B; b += TPB) th[b] = 0;
        __syncthreads();
        // tile histogram
        for (int k = tid; k < tE; k += TPB)
            atomicAdd(&th[((unsigned)dst[ts + k]) >> SHIFT], 1u);
        __syncthreads();
        // single-wave exclusive scan over B buckets (B <= BMAX = 64*4)
        if (tid < 64) {
            int lane = tid;
            unsigned vals[4];
            unsigned tot = 0;
            #pragma unroll
            for (int c = 0; c < 4; ++c) {
                int i = lane * 4 + c;
                vals[c] = (i < B) ? th[i] : 0u;
                tot += vals[c];
            }
            unsigned inc = tot;
            #pragma unroll
            for (int off = 1; off < 64; off <<= 1) {
                unsigned up = __shfl_up(inc, off);
                if (lane >= off) inc += up;
            }
            unsigned run = inc - tot;     // exclusive
            #pragma unroll
            for (int c = 0; c < 4; ++c) {
                int i = lane * 4 + c;
                if (i < B) { basec[i] = run; curt[i] = run; }
                run += vals[c];
            }
        }
        __syncthreads();
        // compute payloads, place bucket-sorted into LDS stage
        for (int k = tid; k < tE; k += TPB) {
            int e = ts + k;
            int s_ = nt_i(&src[e]);
            unsigned d = (unsigned)dst[e];
            float l = nl[s_];
            float p = __expf(TEMP * nt_f(&ew[e]) * l);
            float ow, ox, oy, oz;
            hamilton(nt_f4(&erq[e]), nq[s_], ow, ox, oy, oz);
            unsigned b = d >> SHIFT;
            unsigned pos = atomicAdd(&curt[b], 1u);
            uint4 pk;
            pk.x = (d & (GSZ - 1)) | (f2h(p) << 16);
            pk.y = f2h(p * l)  | (f2h(p * ow) << 16);
            pk.z = f2h(p * ox) | (f2h(p * oy) << 16);
            pk.w = f2h(p * oz) | (b << 16);          // bucket id in spare bits
            stage[pos] = pk;
        }
        __syncthreads();
        // flush in sorted order: consecutive lanes -> consecutive slots
        for (int k = tid; k < tE; k += TPB) {
            uint4 pk = stage[k];
            unsigned b = pk.w >> 16;
            buckets[gcur[b] + ((unsigned)k - basec[b])] = pk;
        }
        __syncthreads();
        for (int b = tid; b < B; b += TPB) gcur[b] += th[b];
        __syncthreads();
    }
}

// ---------- pass G: LDS counting sort per tile + register segmented reduce ----------
// No fp atomics anywhere. Per 4096-record tile (held in registers, 4/thread):
//   u32 count -> wave-0 scan -> u32-cursor placement into sorted LDS order ->
//   thread j walks node j's contiguous run, accumulating 6 floats in registers.
// Finalize (self term + normalize) fused at the end.
__global__ void __launch_bounds__(GTPB)
gather_sort_kernel(const float* __restrict__ nl, const float4* __restrict__ nq,
                   const unsigned* __restrict__ offsets,
                   const uint4* __restrict__ buckets,
                   float4* __restrict__ out_q, float* __restrict__ out_l, int N) {
    __shared__ unsigned s0a[GT];        // 16 KB  p | poz<<16
    __shared__ unsigned s1a[GT];        // 16 KB  pl | pow<<16
    __shared__ unsigned s2a[GT];        // 16 KB  pox | poy<<16
    __shared__ unsigned cnt[GSZ];       //  2 KB  count, then cursor
    __shared__ unsigned base[GSZ + 1];  //  2 KB  run starts

    int b = blockIdx.x, tid = threadIdx.x;
    unsigned q0 = offsets[b], q1 = offsets[b + 1];
    int M = (int)(q1 - q0);

    float accZ = 0.f, accL = 0.f, accW = 0.f, accX = 0.f, accY = 0.f, accV = 0.f;

    for (int t0 = 0; t0 < M; t0 += GT) {
        int tGT = M - t0; if (tGT > GT) tGT = GT;
        for (int i = tid; i < GSZ; i += GTPB) cnt[i] = 0;
        __syncthreads();

        // load tile into registers + u32 count histogram
        uint4 pk0, pk1, pk2, pk3;
        int i0 = tid, i1 = tid + GTPB, i2 = tid + 2 * GTPB, i3 = tid + 3 * GTPB;
        if (i0 < tGT) { pk0 = nt_u4(&buckets[q0 + t0 + i0]); atomicAdd(&cnt[pk0.x & (GSZ-1)], 1u); }
        if (i1 < tGT) { pk1 = nt_u4(&buckets[q0 + t0 + i1]); atomicAdd(&cnt[pk1.x & (GSZ-1)], 1u); }
        if (i2 < tGT) { pk2 = nt_u4(&buckets[q0 + t0 + i2]); atomicAdd(&cnt[pk2.x & (GSZ-1)], 1u); }
        if (i3 < tGT) { pk3 = nt_u4(&buckets[q0 + t0 + i3]); atomicAdd(&cnt[pk3.x & (GSZ-1)], 1u); }
        __syncthreads();

        // wave-0 exclusive scan of 512 counts (8 per lane + shfl)
        if (tid < 64) {
            unsigned vals[8], tot = 0;
            #pragma unroll
            for (int c = 0; c < 8; ++c) { vals[c] = cnt[tid * 8 + c]; tot += vals[c]; }
            unsigned inc = tot;
            #pragma unroll
            for (int off = 1; off < 64; off <<= 1) {
                unsigned up = __shfl_up(inc, off);
                if (tid >= off) inc += up;
            }
            unsigned run = inc - tot;     // exclusive
            #pragma unroll
            for (int c = 0; c < 8; ++c) {
                base[tid * 8 + c] = run;
                cnt[tid * 8 + c]  = run;  // becomes cursor
                run += vals[c];
            }
            if (tid == 63) base[GSZ] = run;   // = tGT
        }
        __syncthreads();

        // place records at sorted positions (u32 cursor atomic)
        if (i0 < tGT) { unsigned p = atomicAdd(&cnt[pk0.x & (GSZ-1)], 1u);
                        s0a[p] = (pk0.x >> 16) | (pk0.w << 16); s1a[p] = pk0.y; s2a[p] = pk0.z; }
        if (i1 < tGT) { unsigned p = atomicAdd(&cnt[pk1.x & (GSZ-1)], 1u);
                        s0a[p] = (pk1.x >> 16) | (pk1.w << 16); s1a[p] = pk1.y; s2a[p] = pk1.z; }
        if (i2 < tGT) { unsigned p = atomicAdd(&cnt[pk2.x & (GSZ-1)], 1u);
                        s0a[p] = (pk2.x >> 16) | (pk2.w << 16); s1a[p] = pk2.y; s2a[p] = pk2.z; }
        if (i3 < tGT) { unsigned p = atomicAdd(&cnt[pk3.x & (GSZ-1)], 1u);
                        s0a[p] = (pk3.x >> 16) | (pk3.w << 16); s1a[p] = pk3.y; s2a[p] = pk3.z; }
        __syncthreads();

        // segmented reduce: thread j owns node j, contiguous LDS run
        if (tid < GSZ) {
            unsigned lo = base[tid], hi = base[tid + 1];
            for (unsigned p = lo; p < hi; ++p) {
                unsigned a = s0a[p], d = s1a[p], e = s2a[p];
                accZ += h2f(a);        accV += h2f(a >> 16);
                accL += h2f(d);        accW += h2f(d >> 16);
                accX += h2f(e);        accY += h2f(e >> 16);
            }
        }
        __syncthreads();
    }

    // fused finalize: self term + normalize
    if (tid < GSZ) {
        int n = b * GSZ + tid;
        if (n < N) {
            float l  = nl[n];
            float ps = __expf(TEMP * l);
            float Z  = accZ + ps;
            float sl = accL + ps * l;
            float4 q = nq[n];
            float qw = accW + ps * q.x;
            float qx = accX + ps * q.y;
            float qy = accY + ps * q.z;
            float qz = accV + ps * q.w;
            float inv = 1.0f / Z;
            qw *= inv; qx *= inv; qy *= inv; qz *= inv;
            float norm = fmaxf(sqrtf(qw*qw + qx*qx + qy*qy + qz*qz), 1e-12f);
            float rn = 1.0f / norm;
            out_q[n] = make_float4(qw * rn, qx * rn, qy * rn, qz * rn);
            out_l[n] = sl * inv;
        }
    }
}

// ---------------- fallback path (R3) ----------------
__global__ void __launch_bounds__(256)
scatter_kernel(const int* __restrict__ dst, int* __restrict__ cnt,
               int* __restrict__ bucket, int cap,
               const float* __restrict__ node_levels, const float4* __restrict__ node_q,
               const float4* __restrict__ edge_rel_q, const float* __restrict__ edge_w,
               const int* __restrict__ src, float* __restrict__ side, int E) {
    int e = blockIdx.x * blockDim.x + threadIdx.x;
    if (e >= E) return;
    int d = dst[e];
    int slot = atomicAdd(&cnt[d], 1);
    if (slot < cap) {
        bucket[(long long)d * cap + slot] = e;
    } else {
        int s = src[e];
        float l = node_levels[s];
        float p = __expf(TEMP * edge_w[e] * l);
        float ow, ox, oy, oz;
        hamilton(edge_rel_q[e], node_q[s], ow, ox, oy, oz);
        float* rec = side + 6 * (long long)d;
        pk_fadd(rec + 0, p,      p * l);
        pk_fadd(rec + 2, p * ow, p * ox);
        pk_fadd(rec + 4, p * oy, p * oz);
    }
}

__global__ void __launch_bounds__(256)
gather_kernel(const float* __restrict__ node_levels, const float4* __restrict__ node_q,
              const float4* __restrict__ edge_rel_q, const float* __restrict__ edge_w,
              const int* __restrict__ src, const int* __restrict__ cnt,
              const int* __restrict__ bucket, int cap, const float* __restrict__ side,
              float4* __restrict__ out_q, float* __restrict__ out_l, int N) {
    int tid  = blockIdx.x * blockDim.x + threadIdx.x;
    int wave = tid >> 6, lane = tid & 63, half = lane >> 5, sub = lane & 31;
    int n = wave * 2 + half;
    float aZ = 0.f, aL = 0.f, a0 = 0.f, a1 = 0.f, a2 = 0.f, a3 = 0.f;
    if (n < N) {
        int deg = cnt[n]; if (deg > cap) deg = cap;
        const int* bkt = bucket + (long long)n * cap;
        for (int s = sub; s < deg; s += 32) {
            int e = bkt[s];
            int sn = src[e];
            float l = node_levels[sn];
            float p = __expf(TEMP * edge_w[e] * l);
            float ow, ox, oy, oz;
            hamilton(edge_rel_q[e], node_q[sn], ow, ox, oy, oz);
            aZ += p; aL += p * l; a0 += p * ow; a1 += p * ox; a2 += p * oy; a3 += p * oz;
        }
    }
    for (int m = 16; m; m >>= 1) {
        aZ += __shfl_xor(aZ, m); aL += __shfl_xor(aL, m);
        a0 += __shfl_xor(a0, m); a1 += __shfl_xor(a1, m);
        a2 += __shfl_xor(a2, m); a3 += __shfl_xor(a3, m);
    }
    if (sub == 0 && n < N) {
        const float* rec = side + 6 * (long long)n;
        float l  = node_levels[n];
        float ps = __expf(TEMP * l);
        float Z  = aZ + rec[0] + ps;
        float sl = aL + rec[1] + ps * l;
        float4 q = node_q[n];
        float qw = a0 + rec[2] + ps * q.x;
        float qx = a1 + rec[3] + ps * q.y;
        float qy = a2 + rec[4] + ps * q.z;
        float qz = a3 + rec[5] + ps * q.w;
        float inv = 1.0f / Z;
        qw *= inv; qx *= inv; qy *= inv; qz *= inv;
        float norm = fmaxf(sqrtf(qw*qw + qx*qx + qy*qy + qz*qz), 1e-12f);
        float rn = 1.0f / norm;
        out_q[n] = make_float4(qw * rn, qx * rn, qy * rn, qz * rn);
        out_l[n] = sl * inv;
    }
}

extern "C" void kernel_launch(void* const* d_in, const int* in_sizes, int n_in,
                              void* d_out, int out_size, void* d_ws, size_t ws_size,
                              hipStream_t stream) {
    const float*  node_levels = (const float*)d_in[0];
    const float4* node_q      = (const float4*)d_in[1];
    const float4* edge_rel_q  = (const float4*)d_in[2];
    const float*  edge_w      = (const float*)d_in[3];
    const int*    src         = (const int*)d_in[4];
    const int*    dst         = (const int*)d_in[5];

    const int N = in_sizes[0];
    const int E = in_sizes[3];

    const int B = (N + GSZ - 1) / GSZ;            // coarse buckets
    const int span = (E + NBLK - 1) / NBLK;

    // ws layout: blkhist[B*NBLK] u32 | totals[B] | offsets[B+1] | pad | buckets[E] uint4
    size_t head_elems   = (size_t)B * NBLK + B + (B + 1);
    size_t buckets_byte = (head_elems * 4 + 15) & ~(size_t)15;
    size_t need         = buckets_byte + (size_t)E * 16;

    if (need <= ws_size && B <= BMAX) {
        unsigned* blkhist = (unsigned*)d_ws;
        unsigned* totals  = blkhist + (size_t)B * NBLK;
        unsigned* offsets = totals + B;
        uint4*    buckets = (uint4*)((char*)d_ws + buckets_byte);

        hist_kernel<<<NBLK, HTPB, B * 4, stream>>>(dst, blkhist, E, B, span);
        scan_blocks_kernel<<<B, NBLK, 0, stream>>>(blkhist, totals);
        scan_totals_kernel<<<1, 1024, 0, stream>>>(totals, offsets, B);
        scatter_sort_kernel<<<NBLK, TPB, 0, stream>>>(
            node_levels, node_q, edge_rel_q, edge_w, src, dst,
            blkhist, offsets, buckets, E, B, span);
        gather_sort_kernel<<<B, GTPB, 0, stream>>>(
            node_levels, node_q, offsets, buckets,
            (float4*)d_out, (float*)d_out + 4 * (long long)N, N);
    } else {
        // R3 fallback
        const int tpb = 256;
        size_t cnt_elems  = ((size_t)N + 3) & ~(size_t)3;
        size_t side_elems = 6 * (size_t)N;
        size_t head_bytes = (cnt_elems + side_elems) * 4;
        int cap = 0;
        for (int c : {128, 64}) {
            if (head_bytes + (size_t)N * c * 4 <= ws_size) { cap = c; break; }
        }
        int*   cnt    = (int*)d_ws;
        float* side   = (float*)d_ws + cnt_elems;
        int*   bucket = (int*)d_ws + cnt_elems + side_elems;
        hipMemsetAsync(d_ws, 0, head_bytes, stream);
        scatter_kernel<<<(E + tpb - 1) / tpb, tpb, 0, stream>>>(
            dst, cnt, bucket, cap, node_levels, node_q, edge_rel_q, edge_w, src, side, E);
        int waves  = (N + 1) / 2;
        int blocks = (waves * 64 + tpb - 1) / tpb;
        gather_kernel<<<blocks, tpb, 0, stream>>>(
            node_levels, node_q, edge_rel_q, edge_w, src, cnt, bucket, cap, side,
            (float4*)d_out, (float*)d_out + 4 * (long long)N, N);
    }
}

// Round 5
// 215.210 us; speedup vs baseline: 1.5531x; 1.0621x over previous
//
#include <hip/hip_runtime.h>
#include <hip/hip_fp16.h>

#define TEMP 10.0f
#define TPB 512           // scatter block size
#define NBLK 768          // scatter grid = 3 blocks/CU exactly (45KB LDS -> 3 resident)
#define SHIFT 9
#define GSZ 512           // nodes per bucket = 1<<SHIFT
#define BMAX 256          // max buckets (bucket tag fits in 16 spare bits of pk.w)
#define TILE 2112         // edges per scatter tile (span 4167 -> 2 balanced tiles)
#define GTPB 1024         // gather block size
#define GT 4096           // records per gather tile (4 regs/thread)
#define OVCAP 16384       // overflow list capacity (records)
#define SPILL 0xFFFFFFFFu

typedef float v2f  __attribute__((ext_vector_type(2)));
typedef float vf4  __attribute__((ext_vector_type(4)));
typedef unsigned uv4 __attribute__((ext_vector_type(4)));

__device__ __forceinline__ int   nt_i (const int* p)   { return __builtin_nontemporal_load(p); }
__device__ __forceinline__ float nt_f (const float* p) { return __builtin_nontemporal_load(p); }
__device__ __forceinline__ float4 nt_f4(const float4* p) {
    vf4 v = __builtin_nontemporal_load((const vf4*)p);
    return make_float4(v.x, v.y, v.z, v.w);
}
__device__ __forceinline__ uint4 nt_u4(const uint4* p) {
    uv4 v = __builtin_nontemporal_load((const uv4*)p);
    uint4 r; r.x = v.x; r.y = v.y; r.z = v.z; r.w = v.w; return r;
}

__device__ __forceinline__ void pk_fadd(float* p, float a, float b) {
#if __has_builtin(__builtin_amdgcn_global_atomic_fadd_v2f32)
    v2f v; v.x = a; v.y = b;
    __builtin_amdgcn_global_atomic_fadd_v2f32(
        (__attribute__((address_space(1))) v2f*)p, v);
#else
    atomicAdd(p, a); atomicAdd(p + 1, b);
#endif
}

__device__ __forceinline__ void hamilton(float4 a, float4 b,
                                         float& ow, float& ox, float& oy, float& oz) {
    ow = a.x*b.x - a.y*b.y - a.z*b.z - a.w*b.w;
    ox = a.x*b.y + a.y*b.x + a.z*b.w - a.w*b.z;
    oy = a.x*b.z - a.y*b.w + a.z*b.x + a.w*b.y;
    oz = a.x*b.w + a.y*b.z - a.z*b.y + a.w*b.x;
}

__device__ __forceinline__ unsigned f2h(float x) {
    return (unsigned)__half_as_ushort(__float2half_rn(x));
}
__device__ __forceinline__ float h2f(unsigned u) {
    return __half2float(__ushort_as_half((unsigned short)(u & 0xFFFFu)));
}

// ---------- pass S: tile-sorted placement into fixed per-bucket slices ----------
// No hist/scan front: each tile reserves a contiguous range inside bucket b's
// fixed slice [b*CAPB, (b+1)*CAPB) with ONE global u32 atomicAdd per (tile,bucket).
// Records beyond CAPB spill to a global overflow list (statistically empty:
// CAPB ~ mean + 7 sigma for uniform dst); gather replays the list, so spills
// stay correct, just slower.
__global__ void __launch_bounds__(TPB)
scatter_cursor_kernel(const float* __restrict__ nl, const float4* __restrict__ nq,
                      const float4* __restrict__ erq, const float* __restrict__ ew,
                      const int* __restrict__ src, const int* __restrict__ dst,
                      unsigned* __restrict__ cursors,   // [B] cursors, [B] = ovcnt
                      uint4* __restrict__ ov,
                      uint4* __restrict__ buckets,
                      int E, int B, int span, int CAPB) {
    __shared__ uint4    stage[TILE];     // 33 KB
    __shared__ unsigned gslot[TILE];     // 8.25 KB
    __shared__ unsigned th[BMAX];        // 1 KB each below
    __shared__ unsigned basec[BMAX];
    __shared__ unsigned curt[BMAX];
    __shared__ unsigned gbase[BMAX];

    int blk = blockIdx.x, tid = threadIdx.x;
    int start = blk * span;
    int end = start + span; if (end > E) end = E;

    for (int ts = start; ts < end; ts += TILE) {
        int tE = end - ts; if (tE > TILE) tE = TILE;
        for (int b = tid; b < B; b += TPB) th[b] = 0;
        __syncthreads();
        // tile histogram
        for (int k = tid; k < tE; k += TPB)
            atomicAdd(&th[((unsigned)dst[ts + k]) >> SHIFT], 1u);
        __syncthreads();
        // reserve contiguous per-bucket ranges (global u32 atomics, low contention)
        for (int b = tid; b < B; b += TPB)
            gbase[b] = atomicAdd(&cursors[b], th[b]);
        // single-wave exclusive scan over B buckets (B <= BMAX = 64*4)
        if (tid < 64) {
            int lane = tid;
            unsigned vals[4];
            unsigned tot = 0;
            #pragma unroll
            for (int c = 0; c < 4; ++c) {
                int i = lane * 4 + c;
                vals[c] = (i < B) ? th[i] : 0u;
                tot += vals[c];
            }
            unsigned inc = tot;
            #pragma unroll
            for (int off = 1; off < 64; off <<= 1) {
                unsigned up = __shfl_up(inc, off);
                if (lane >= off) inc += up;
            }
            unsigned run = inc - tot;     // exclusive
            #pragma unroll
            for (int c = 0; c < 4; ++c) {
                int i = lane * 4 + c;
                if (i < B) { basec[i] = run; curt[i] = run; }
                run += vals[c];
            }
        }
        __syncthreads();
        // compute payloads, place bucket-sorted into LDS stage, precompute slot
        for (int k = tid; k < tE; k += TPB) {
            int e = ts + k;
            int s_ = nt_i(&src[e]);
            unsigned d = (unsigned)dst[e];
            float l = nl[s_];
            float p = __expf(TEMP * nt_f(&ew[e]) * l);
            float ow, ox, oy, oz;
            hamilton(nt_f4(&erq[e]), nq[s_], ow, ox, oy, oz);
            unsigned b = d >> SHIFT;
            unsigned pos = atomicAdd(&curt[b], 1u);
            uint4 pk;
            pk.x = (d & (GSZ - 1)) | (f2h(p) << 16);
            pk.y = f2h(p * l)  | (f2h(p * ow) << 16);
            pk.z = f2h(p * ox) | (f2h(p * oy) << 16);
            pk.w = f2h(p * oz) | (b << 16);          // bucket tag (needed for spills)
            stage[pos] = pk;
            unsigned within = gbase[b] + (pos - basec[b]);
            gslot[pos] = (within < (unsigned)CAPB)
                       ? ((unsigned)b * (unsigned)CAPB + within) : SPILL;
        }
        __syncthreads();
        // flush in sorted order: consecutive lanes -> consecutive slots
        for (int k = tid; k < tE; k += TPB) {
            uint4 pk = stage[k];
            unsigned s = gslot[k];
            if (s != SPILL) {
                buckets[s] = pk;
            } else {
                unsigned i = atomicAdd(&cursors[B], 1u);
                if (i < (unsigned)OVCAP) ov[i] = pk;
            }
        }
        // no trailing barrier needed: next tile's first barrier (after th-zero)
        // orders flush-completion before stage reuse
    }
}

// ---------- pass G: LDS counting sort per tile + register segmented reduce ----------
// No fp atomics anywhere. Per 4096-record tile (held in registers, 4/thread):
//   u32 count -> wave-0 scan -> u32-cursor placement into sorted LDS order ->
//   thread j walks node j's contiguous run, accumulating 6 floats in registers.
// Overflow list replay + fused finalize (self term + normalize) at the end.
__global__ void __launch_bounds__(GTPB)
gather_sort_kernel(const float* __restrict__ nl, const float4* __restrict__ nq,
                   const unsigned* __restrict__ cursors,
                   const uint4* __restrict__ ov,
                   const uint4* __restrict__ buckets,
                   float4* __restrict__ out_q, float* __restrict__ out_l,
                   int N, int B, int CAPB) {
    __shared__ unsigned s0a[GT];        // 16 KB  p | poz<<16
    __shared__ unsigned s1a[GT];        // 16 KB  pl | pow<<16
    __shared__ unsigned s2a[GT];        // 16 KB  pox | poy<<16
    __shared__ unsigned cnt[GSZ];       //  2 KB  count, then cursor
    __shared__ unsigned base[GSZ + 1];  //  2 KB  run starts

    int b = blockIdx.x, tid = threadIdx.x;
    unsigned total = cursors[b];
    int M = (int)(total < (unsigned)CAPB ? total : (unsigned)CAPB);
    const uint4* seg = buckets + (size_t)b * (size_t)CAPB;

    float accZ = 0.f, accL = 0.f, accW = 0.f, accX = 0.f, accY = 0.f, accV = 0.f;

    for (int t0 = 0; t0 < M; t0 += GT) {
        int tGT = M - t0; if (tGT > GT) tGT = GT;
        for (int i = tid; i < GSZ; i += GTPB) cnt[i] = 0;
        __syncthreads();

        // load tile into registers + u32 count histogram
        uint4 pk0, pk1, pk2, pk3;
        int i0 = tid, i1 = tid + GTPB, i2 = tid + 2 * GTPB, i3 = tid + 3 * GTPB;
        if (i0 < tGT) { pk0 = nt_u4(&seg[t0 + i0]); atomicAdd(&cnt[pk0.x & (GSZ-1)], 1u); }
        if (i1 < tGT) { pk1 = nt_u4(&seg[t0 + i1]); atomicAdd(&cnt[pk1.x & (GSZ-1)], 1u); }
        if (i2 < tGT) { pk2 = nt_u4(&seg[t0 + i2]); atomicAdd(&cnt[pk2.x & (GSZ-1)], 1u); }
        if (i3 < tGT) { pk3 = nt_u4(&seg[t0 + i3]); atomicAdd(&cnt[pk3.x & (GSZ-1)], 1u); }
        __syncthreads();

        // wave-0 exclusive scan of 512 counts (8 per lane + shfl)
        if (tid < 64) {
            unsigned vals[8], tot = 0;
            #pragma unroll
            for (int c = 0; c < 8; ++c) { vals[c] = cnt[tid * 8 + c]; tot += vals[c]; }
            unsigned inc = tot;
            #pragma unroll
            for (int off = 1; off < 64; off <<= 1) {
                unsigned up = __shfl_up(inc, off);
                if (tid >= off) inc += up;
            }
            unsigned run = inc - tot;     // exclusive
            #pragma unroll
            for (int c = 0; c < 8; ++c) {
                base[tid * 8 + c] = run;
                cnt[tid * 8 + c]  = run;  // becomes cursor
                run += vals[c];
            }
            if (tid == 63) base[GSZ] = run;   // = tGT
        }
        __syncthreads();

        // place records at sorted positions (u32 cursor atomic)
        if (i0 < tGT) { unsigned p = atomicAdd(&cnt[pk0.x & (GSZ-1)], 1u);
                        s0a[p] = (pk0.x >> 16) | (pk0.w << 16); s1a[p] = pk0.y; s2a[p] = pk0.z; }
        if (i1 < tGT) { unsigned p = atomicAdd(&cnt[pk1.x & (GSZ-1)], 1u);
                        s0a[p] = (pk1.x >> 16) | (pk1.w << 16); s1a[p] = pk1.y; s2a[p] = pk1.z; }
        if (i2 < tGT) { unsigned p = atomicAdd(&cnt[pk2.x & (GSZ-1)], 1u);
                        s0a[p] = (pk2.x >> 16) | (pk2.w << 16); s1a[p] = pk2.y; s2a[p] = pk2.z; }
        if (i3 < tGT) { unsigned p = atomicAdd(&cnt[pk3.x & (GSZ-1)], 1u);
                        s0a[p] = (pk3.x >> 16) | (pk3.w << 16); s1a[p] = pk3.y; s2a[p] = pk3.z; }
        __syncthreads();

        // segmented reduce: thread j owns node j, contiguous LDS run
        if (tid < GSZ) {
            unsigned lo = base[tid], hi = base[tid + 1];
            for (unsigned p = lo; p < hi; ++p) {
                unsigned a = s0a[p], d = s1a[p], e = s2a[p];
                accZ += h2f(a);        accV += h2f(a >> 16);
                accL += h2f(d);        accW += h2f(d >> 16);
                accX += h2f(e);        accY += h2f(e >> 16);
            }
        }
        __syncthreads();
    }

    // overflow replay (expected zero-length) + fused finalize
    if (tid < GSZ) {
        unsigned ovc = cursors[B]; if (ovc > (unsigned)OVCAP) ovc = OVCAP;
        for (unsigned i = 0; i < ovc; ++i) {
            uint4 pk = ov[i];
            if ((pk.w >> 16) == (unsigned)b && (int)(pk.x & (GSZ - 1)) == tid) {
                accZ += h2f(pk.x >> 16); accV += h2f(pk.w);
                accL += h2f(pk.y);       accW += h2f(pk.y >> 16);
                accX += h2f(pk.z);       accY += h2f(pk.z >> 16);
            }
        }
        int n = b * GSZ + tid;
        if (n < N) {
            float l  = nl[n];
            float ps = __expf(TEMP * l);
            float Z  = accZ + ps;
            float sl = accL + ps * l;
            float4 q = nq[n];
            float qw = accW + ps * q.x;
            float qx = accX + ps * q.y;
            float qy = accY + ps * q.z;
            float qz = accV + ps * q.w;
            float inv = 1.0f / Z;
            qw *= inv; qx *= inv; qy *= inv; qz *= inv;
            float norm = fmaxf(sqrtf(qw*qw + qx*qx + qy*qy + qz*qz), 1e-12f);
            float rn = 1.0f / norm;
            out_q[n] = make_float4(qw * rn, qx * rn, qy * rn, qz * rn);
            out_l[n] = sl * inv;
        }
    }
}

// ---------------- fallback path (R3) ----------------
__global__ void __launch_bounds__(256)
scatter_kernel(const int* __restrict__ dst, int* __restrict__ cnt,
               int* __restrict__ bucket, int cap,
               const float* __restrict__ node_levels, const float4* __restrict__ node_q,
               const float4* __restrict__ edge_rel_q, const float* __restrict__ edge_w,
               const int* __restrict__ src, float* __restrict__ side, int E) {
    int e = blockIdx.x * blockDim.x + threadIdx.x;
    if (e >= E) return;
    int d = dst[e];
    int slot = atomicAdd(&cnt[d], 1);
    if (slot < cap) {
        bucket[(long long)d * cap + slot] = e;
    } else {
        int s = src[e];
        float l = node_levels[s];
        float p = __expf(TEMP * edge_w[e] * l);
        float ow, ox, oy, oz;
        hamilton(edge_rel_q[e], node_q[s], ow, ox, oy, oz);
        float* rec = side + 6 * (long long)d;
        pk_fadd(rec + 0, p,      p * l);
        pk_fadd(rec + 2, p * ow, p * ox);
        pk_fadd(rec + 4, p * oy, p * oz);
    }
}

__global__ void __launch_bounds__(256)
gather_kernel(const float* __restrict__ node_levels, const float4* __restrict__ node_q,
              const float4* __restrict__ edge_rel_q, const float* __restrict__ edge_w,
              const int* __restrict__ src, const int* __restrict__ cnt,
              const int* __restrict__ bucket, int cap, const float* __restrict__ side,
              float4* __restrict__ out_q, float* __restrict__ out_l, int N) {
    int tid  = blockIdx.x * blockDim.x + threadIdx.x;
    int wave = tid >> 6, lane = tid & 63, half = lane >> 5, sub = lane & 31;
    int n = wave * 2 + half;
    float aZ = 0.f, aL = 0.f, a0 = 0.f, a1 = 0.f, a2 = 0.f, a3 = 0.f;
    if (n < N) {
        int deg = cnt[n]; if (deg > cap) deg = cap;
        const int* bkt = bucket + (long long)n * cap;
        for (int s = sub; s < deg; s += 32) {
            int e = bkt[s];
            int sn = src[e];
            float l = node_levels[sn];
            float p = __expf(TEMP * edge_w[e] * l);
            float ow, ox, oy, oz;
            hamilton(edge_rel_q[e], node_q[sn], ow, ox, oy, oz);
            aZ += p; aL += p * l; a0 += p * ow; a1 += p * ox; a2 += p * oy; a3 += p * oz;
        }
    }
    for (int m = 16; m; m >>= 1) {
        aZ += __shfl_xor(aZ, m); aL += __shfl_xor(aL, m);
        a0 += __shfl_xor(a0, m); a1 += __shfl_xor(a1, m);
        a2 += __shfl_xor(a2, m); a3 += __shfl_xor(a3, m);
    }
    if (sub == 0 && n < N) {
        const float* rec = side + 6 * (long long)n;
        float l  = node_levels[n];
        float ps = __expf(TEMP * l);
        float Z  = aZ + rec[0] + ps;
        float sl = aL + rec[1] + ps * l;
        float4 q = node_q[n];
        float qw = a0 + rec[2] + ps * q.x;
        float qx = a1 + rec[3] + ps * q.y;
        float qy = a2 + rec[4] + ps * q.z;
        float qz = a3 + rec[5] + ps * q.w;
        float inv = 1.0f / Z;
        qw *= inv; qx *= inv; qy *= inv; qz *= inv;
        float norm = fmaxf(sqrtf(qw*qw + qx*qx + qy*qy + qz*qz), 1e-12f);
        float rn = 1.0f / norm;
        out_q[n] = make_float4(qw * rn, qx * rn, qy * rn, qz * rn);
        out_l[n] = sl * inv;
    }
}

extern "C" void kernel_launch(void* const* d_in, const int* in_sizes, int n_in,
                              void* d_out, int out_size, void* d_ws, size_t ws_size,
                              hipStream_t stream) {
    const float*  node_levels = (const float*)d_in[0];
    const float4* node_q      = (const float4*)d_in[1];
    const float4* edge_rel_q  = (const float4*)d_in[2];
    const float*  edge_w      = (const float*)d_in[3];
    const int*    src         = (const int*)d_in[4];
    const int*    dst         = (const int*)d_in[5];

    const int N = in_sizes[0];
    const int E = in_sizes[3];

    const int B = (N + GSZ - 1) / GSZ;            // coarse buckets
    const int span = (E + NBLK - 1) / NBLK;

    // ws layout: cursors[B] u32 | ovcnt u32 | pad | ov[OVCAP] uint4 | buckets[B*CAPB] uint4
    size_t head  = (((size_t)(B + 1) * 4) + 15) & ~(size_t)15;
    size_t fixed = head + (size_t)OVCAP * 16;

    int CAPB = 0;
    bool ok = false;
    if (B >= 1 && B <= BMAX && ws_size > fixed) {
        size_t capb = (ws_size - fixed) / ((size_t)B * 16);
        long long mean = (E + B) / B;
        if ((long long)capb >= mean + 2048) {     // >= mean + ~16 sigma for uniform dst
            ok = true;
            CAPB = (int)((capb < 0x7FFFFFFF) ? capb : 0x7FFFFFFF);
        }
    }

    if (ok) {
        unsigned* cursors = (unsigned*)d_ws;
        uint4*    ov      = (uint4*)((char*)d_ws + head);
        uint4*    buckets = ov + OVCAP;

        hipMemsetAsync(d_ws, 0, (size_t)(B + 1) * 4, stream);
        scatter_cursor_kernel<<<NBLK, TPB, 0, stream>>>(
            node_levels, node_q, edge_rel_q, edge_w, src, dst,
            cursors, ov, buckets, E, B, span, CAPB);
        gather_sort_kernel<<<B, GTPB, 0, stream>>>(
            node_levels, node_q, cursors, ov, buckets,
            (float4*)d_out, (float*)d_out + 4 * (long long)N, N, B, CAPB);
    } else {
        // R3 fallback
        const int tpb = 256;
        size_t cnt_elems  = ((size_t)N + 3) & ~(size_t)3;
        size_t side_elems = 6 * (size_t)N;
        size_t head_bytes = (cnt_elems + side_elems) * 4;
        int cap = 0;
        for (int c : {128, 64}) {
            if (head_bytes + (size_t)N * c * 4 <= ws_size) { cap = c; break; }
        }
        int*   cnt    = (int*)d_ws;
        float* side   = (float*)d_ws + cnt_elems;
        int*   bucket = (int*)d_ws + cnt_elems + side_elems;
        hipMemsetAsync(d_ws, 0, head_bytes, stream);
        scatter_kernel<<<(E + tpb - 1) / tpb, tpb, 0, stream>>>(
            dst, cnt, bucket, cap, node_levels, node_q, edge_rel_q, edge_w, src, side, E);
        int waves  = (N + 1) / 2;
        int blocks = (waves * 64 + tpb - 1) / tpb;
        gather_kernel<<<blocks, tpb, 0, stream>>>(
            node_levels, node_q, edge_rel_q, edge_w, src, cnt, bucket, cap, side,
            (float4*)d_out, (float*)d_out + 4 * (long long)N, N);
    }
}

// Round 6
// 209.713 us; speedup vs baseline: 1.5938x; 1.0262x over previous
//
#include <hip/hip_runtime.h>
#include <hip/hip_fp16.h>

#define TEMP 10.0f
#define TPB 512           // scatter block size
#define HTPB 256          // hist block size
#define NBLK 1024         // hist/scatter grid -> span 3125 = 2 balanced tiles
#define SHIFT 9
#define GSZ 512           // nodes per bucket = 1<<SHIFT
#define BMAX 256          // max buckets
#define TILE 1568         // edges per scatter tile (34.6KB LDS -> 4 blocks/CU)
#define GTPB 1024         // gather block size
#define GT 4096           // records per gather tile (4 regs/thread)

typedef float v2f  __attribute__((ext_vector_type(2)));
typedef float vf4  __attribute__((ext_vector_type(4)));
typedef unsigned uv4 __attribute__((ext_vector_type(4)));

__device__ __forceinline__ int   nt_i (const int* p)   { return __builtin_nontemporal_load(p); }
__device__ __forceinline__ float nt_f (const float* p) { return __builtin_nontemporal_load(p); }
__device__ __forceinline__ float4 nt_f4(const float4* p) {
    vf4 v = __builtin_nontemporal_load((const vf4*)p);
    return make_float4(v.x, v.y, v.z, v.w);
}
__device__ __forceinline__ uint4 nt_u4(const uint4* p) {
    uv4 v = __builtin_nontemporal_load((const uv4*)p);
    uint4 r; r.x = v.x; r.y = v.y; r.z = v.z; r.w = v.w; return r;
}

__device__ __forceinline__ void pk_fadd(float* p, float a, float b) {
#if __has_builtin(__builtin_amdgcn_global_atomic_fadd_v2f32)
    v2f v; v.x = a; v.y = b;
    __builtin_amdgcn_global_atomic_fadd_v2f32(
        (__attribute__((address_space(1))) v2f*)p, v);
#else
    atomicAdd(p, a); atomicAdd(p + 1, b);
#endif
}

__device__ __forceinline__ void hamilton(float4 a, float4 b,
                                         float& ow, float& ox, float& oy, float& oz) {
    ow = a.x*b.x - a.y*b.y - a.z*b.z - a.w*b.w;
    ox = a.x*b.y + a.y*b.x + a.z*b.w - a.w*b.z;
    oy = a.x*b.z - a.y*b.w + a.z*b.x + a.w*b.y;
    oz = a.x*b.w + a.y*b.z - a.z*b.y + a.w*b.x;
}

__device__ __forceinline__ unsigned f2h(float x) {
    return (unsigned)__half_as_ushort(__float2half_rn(x));
}
__device__ __forceinline__ float h2f(unsigned u) {
    return __half2float(__ushort_as_half((unsigned short)(u & 0xFFFFu)));
}

// ---------- pass H: per-block LDS histogram of dst buckets ----------
__global__ void __launch_bounds__(HTPB)
hist_kernel(const int* __restrict__ dst, unsigned* __restrict__ blkhist,
            int E, int B, int span) {
    extern __shared__ unsigned h[];
    for (int i = threadIdx.x; i < B; i += blockDim.x) h[i] = 0;
    __syncthreads();
    int start = blockIdx.x * span;
    int end = start + span; if (end > E) end = E;
    for (int e = start + threadIdx.x; e < end; e += blockDim.x)
        atomicAdd(&h[((unsigned)nt_i(&dst[e])) >> SHIFT], 1u);
    __syncthreads();
    for (int i = threadIdx.x; i < B; i += blockDim.x)
        blkhist[(size_t)i * gridDim.x + blockIdx.x] = h[i];  // bucket-major
}

// ---------- pass P1: exclusive scan across blocks, per bucket ----------
__global__ void __launch_bounds__(1024)
scan_blocks_kernel(unsigned* __restrict__ blkhist, unsigned* __restrict__ totals) {
    __shared__ unsigned s[1024];
    int b = blockIdx.x, t = threadIdx.x, n = blockDim.x;
    unsigned v = blkhist[(size_t)b * n + t];
    s[t] = v; __syncthreads();
    for (int off = 1; off < n; off <<= 1) {
        unsigned add = (t >= off) ? s[t - off] : 0u;
        __syncthreads();
        s[t] += add;
        __syncthreads();
    }
    blkhist[(size_t)b * n + t] = s[t] - v;   // exclusive (local base)
    if (t == n - 1) totals[b] = s[t];
}

// ---------- pass P2: exclusive scan of bucket totals ----------
__global__ void __launch_bounds__(1024)
scan_totals_kernel(const unsigned* __restrict__ totals,
                   unsigned* __restrict__ offsets, int B) {
    __shared__ unsigned s[1024];
    int t = threadIdx.x;
    unsigned v = (t < B) ? totals[t] : 0u;
    s[t] = v; __syncthreads();
    for (int off = 1; off < 1024; off <<= 1) {
        unsigned add = (t >= off) ? s[t - off] : 0u;
        __syncthreads();
        s[t] += add;
        __syncthreads();
    }
    if (t < B) offsets[t] = s[t] - v;
    if (t == B - 1) offsets[B] = s[t];
}

// ---------- pass S: tile-sorted payload placement (R0 pedigree: no global
// atomics in-loop; per-block bases precomputed by the front) ----------
// TILE=1568 -> 34.6KB LDS -> 4 blocks/CU (32 waves, occupancy cap).
__global__ void __launch_bounds__(TPB)
scatter_sort_kernel(const float* __restrict__ nl, const float4* __restrict__ nq,
                    const float4* __restrict__ erq, const float* __restrict__ ew,
                    const int* __restrict__ src, const int* __restrict__ dst,
                    const unsigned* __restrict__ blkhist,
                    const unsigned* __restrict__ offsets,
                    uint4* __restrict__ buckets,
                    int E, int B, int span) {
    __shared__ uint4    stage[TILE];     // 24.5 KB
    __shared__ unsigned gslot[TILE];     //  6.1 KB
    __shared__ unsigned gcur[BMAX];      //  1 KB each below
    __shared__ unsigned th[BMAX];
    __shared__ unsigned basec[BMAX];
    __shared__ unsigned curt[BMAX];

    int blk = blockIdx.x, nb = gridDim.x, tid = threadIdx.x;
    for (int b = tid; b < B; b += TPB)
        gcur[b] = offsets[b] + blkhist[(size_t)b * nb + blk];
    int start = blk * span;
    int end = start + span; if (end > E) end = E;

    for (int ts = start; ts < end; ts += TILE) {
        int tE = end - ts; if (tE > TILE) tE = TILE;
        for (int b = tid; b < B; b += TPB) th[b] = 0;
        __syncthreads();
        // tile histogram
        for (int k = tid; k < tE; k += TPB)
            atomicAdd(&th[((unsigned)dst[ts + k]) >> SHIFT], 1u);
        __syncthreads();
        // single-wave exclusive scan over B buckets (B <= BMAX = 64*4)
        if (tid < 64) {
            int lane = tid;
            unsigned vals[4];
            unsigned tot = 0;
            #pragma unroll
            for (int c = 0; c < 4; ++c) {
                int i = lane * 4 + c;
                vals[c] = (i < B) ? th[i] : 0u;
                tot += vals[c];
            }
            unsigned inc = tot;
            #pragma unroll
            for (int off = 1; off < 64; off <<= 1) {
                unsigned up = __shfl_up(inc, off);
                if (lane >= off) inc += up;
            }
            unsigned run = inc - tot;     // exclusive
            #pragma unroll
            for (int c = 0; c < 4; ++c) {
                int i = lane * 4 + c;
                if (i < B) { basec[i] = run; curt[i] = run; }
                run += vals[c];
            }
        }
        __syncthreads();
        // compute payloads, place bucket-sorted into LDS stage
        for (int k = tid; k < tE; k += TPB) {
            int e = ts + k;
            int s_ = nt_i(&src[e]);
            unsigned d = (unsigned)dst[e];
            float l = nl[s_];
            float p = __expf(TEMP * nt_f(&ew[e]) * l);
            float ow, ox, oy, oz;
            hamilton(nt_f4(&erq[e]), nq[s_], ow, ox, oy, oz);
            unsigned b = d >> SHIFT;
            unsigned pos = atomicAdd(&curt[b], 1u);
            uint4 pk;
            pk.x = (d & (GSZ - 1)) | (f2h(p) << 16);
            pk.y = f2h(p * l)  | (f2h(p * ow) << 16);
            pk.z = f2h(p * ox) | (f2h(p * oy) << 16);
            pk.w = f2h(p * oz);
            stage[pos] = pk;
            gslot[pos] = gcur[b] + (pos - basec[b]);
        }
        __syncthreads();
        // flush in sorted order: consecutive lanes -> consecutive slots
        for (int k = tid; k < tE; k += TPB)
            buckets[gslot[k]] = stage[k];
        __syncthreads();
        for (int b = tid; b < B; b += TPB) gcur[b] += th[b];
        __syncthreads();
    }
}

// ---------- pass G: LDS counting sort per tile + register segmented reduce ----------
// No fp atomics anywhere. Per 4096-record tile (held in registers, 4/thread):
//   u32 count -> wave-0 scan -> u32-cursor placement into sorted LDS order ->
//   thread j walks node j's contiguous run, accumulating 6 floats in registers.
// Finalize (self term + normalize) fused at the end.
__global__ void __launch_bounds__(GTPB)
gather_sort_kernel(const float* __restrict__ nl, const float4* __restrict__ nq,
                   const unsigned* __restrict__ offsets,
                   const uint4* __restrict__ buckets,
                   float4* __restrict__ out_q, float* __restrict__ out_l, int N) {
    __shared__ unsigned s0a[GT];        // 16 KB  p | poz<<16
    __shared__ unsigned s1a[GT];        // 16 KB  pl | pow<<16
    __shared__ unsigned s2a[GT];        // 16 KB  pox | poy<<16
    __shared__ unsigned cnt[GSZ];       //  2 KB  count, then cursor
    __shared__ unsigned base[GSZ + 1];  //  2 KB  run starts

    int b = blockIdx.x, tid = threadIdx.x;
    unsigned q0 = offsets[b], q1 = offsets[b + 1];
    int M = (int)(q1 - q0);

    float accZ = 0.f, accL = 0.f, accW = 0.f, accX = 0.f, accY = 0.f, accV = 0.f;

    for (int t0 = 0; t0 < M; t0 += GT) {
        int tGT = M - t0; if (tGT > GT) tGT = GT;
        for (int i = tid; i < GSZ; i += GTPB) cnt[i] = 0;
        __syncthreads();

        // load tile into registers + u32 count histogram
        uint4 pk0, pk1, pk2, pk3;
        int i0 = tid, i1 = tid + GTPB, i2 = tid + 2 * GTPB, i3 = tid + 3 * GTPB;
        if (i0 < tGT) { pk0 = nt_u4(&buckets[q0 + t0 + i0]); atomicAdd(&cnt[pk0.x & (GSZ-1)], 1u); }
        if (i1 < tGT) { pk1 = nt_u4(&buckets[q0 + t0 + i1]); atomicAdd(&cnt[pk1.x & (GSZ-1)], 1u); }
        if (i2 < tGT) { pk2 = nt_u4(&buckets[q0 + t0 + i2]); atomicAdd(&cnt[pk2.x & (GSZ-1)], 1u); }
        if (i3 < tGT) { pk3 = nt_u4(&buckets[q0 + t0 + i3]); atomicAdd(&cnt[pk3.x & (GSZ-1)], 1u); }
        __syncthreads();

        // wave-0 exclusive scan of 512 counts (8 per lane + shfl)
        if (tid < 64) {
            unsigned vals[8], tot = 0;
            #pragma unroll
            for (int c = 0; c < 8; ++c) { vals[c] = cnt[tid * 8 + c]; tot += vals[c]; }
            unsigned inc = tot;
            #pragma unroll
            for (int off = 1; off < 64; off <<= 1) {
                unsigned up = __shfl_up(inc, off);
                if (tid >= off) inc += up;
            }
            unsigned run = inc - tot;     // exclusive
            #pragma unroll
            for (int c = 0; c < 8; ++c) {
                base[tid * 8 + c] = run;
                cnt[tid * 8 + c]  = run;  // becomes cursor
                run += vals[c];
            }
            if (tid == 63) base[GSZ] = run;   // = tGT
        }
        __syncthreads();

        // place records at sorted positions (u32 cursor atomic)
        if (i0 < tGT) { unsigned p = atomicAdd(&cnt[pk0.x & (GSZ-1)], 1u);
                        s0a[p] = (pk0.x >> 16) | (pk0.w << 16); s1a[p] = pk0.y; s2a[p] = pk0.z; }
        if (i1 < tGT) { unsigned p = atomicAdd(&cnt[pk1.x & (GSZ-1)], 1u);
                        s0a[p] = (pk1.x >> 16) | (pk1.w << 16); s1a[p] = pk1.y; s2a[p] = pk1.z; }
        if (i2 < tGT) { unsigned p = atomicAdd(&cnt[pk2.x & (GSZ-1)], 1u);
                        s0a[p] = (pk2.x >> 16) | (pk2.w << 16); s1a[p] = pk2.y; s2a[p] = pk2.z; }
        if (i3 < tGT) { unsigned p = atomicAdd(&cnt[pk3.x & (GSZ-1)], 1u);
                        s0a[p] = (pk3.x >> 16) | (pk3.w << 16); s1a[p] = pk3.y; s2a[p] = pk3.z; }
        __syncthreads();

        // segmented reduce: thread j owns node j, contiguous LDS run
        if (tid < GSZ) {
            unsigned lo = base[tid], hi = base[tid + 1];
            for (unsigned p = lo; p < hi; ++p) {
                unsigned a = s0a[p], d = s1a[p], e = s2a[p];
                accZ += h2f(a);        accV += h2f(a >> 16);
                accL += h2f(d);        accW += h2f(d >> 16);
                accX += h2f(e);        accY += h2f(e >> 16);
            }
        }
        __syncthreads();
    }

    // fused finalize: self term + normalize
    if (tid < GSZ) {
        int n = b * GSZ + tid;
        if (n < N) {
            float l  = nl[n];
            float ps = __expf(TEMP * l);
            float Z  = accZ + ps;
            float sl = accL + ps * l;
            float4 q = nq[n];
            float qw = accW + ps * q.x;
            float qx = accX + ps * q.y;
            float qy = accY + ps * q.z;
            float qz = accV + ps * q.w;
            float inv = 1.0f / Z;
            qw *= inv; qx *= inv; qy *= inv; qz *= inv;
            float norm = fmaxf(sqrtf(qw*qw + qx*qx + qy*qy + qz*qz), 1e-12f);
            float rn = 1.0f / norm;
            out_q[n] = make_float4(qw * rn, qx * rn, qy * rn, qz * rn);
            out_l[n] = sl * inv;
        }
    }
}

// ---------------- fallback path (R3) ----------------
__global__ void __launch_bounds__(256)
scatter_kernel(const int* __restrict__ dst, int* __restrict__ cnt,
               int* __restrict__ bucket, int cap,
               const float* __restrict__ node_levels, const float4* __restrict__ node_q,
               const float4* __restrict__ edge_rel_q, const float* __restrict__ edge_w,
               const int* __restrict__ src, float* __restrict__ side, int E) {
    int e = blockIdx.x * blockDim.x + threadIdx.x;
    if (e >= E) return;
    int d = dst[e];
    int slot = atomicAdd(&cnt[d], 1);
    if (slot < cap) {
        bucket[(long long)d * cap + slot] = e;
    } else {
        int s = src[e];
        float l = node_levels[s];
        float p = __expf(TEMP * edge_w[e] * l);
        float ow, ox, oy, oz;
        hamilton(edge_rel_q[e], node_q[s], ow, ox, oy, oz);
        float* rec = side + 6 * (long long)d;
        pk_fadd(rec + 0, p,      p * l);
        pk_fadd(rec + 2, p * ow, p * ox);
        pk_fadd(rec + 4, p * oy, p * oz);
    }
}

__global__ void __launch_bounds__(256)
gather_kernel(const float* __restrict__ node_levels, const float4* __restrict__ node_q,
              const float4* __restrict__ edge_rel_q, const float* __restrict__ edge_w,
              const int* __restrict__ src, const int* __restrict__ cnt,
              const int* __restrict__ bucket, int cap, const float* __restrict__ side,
              float4* __restrict__ out_q, float* __restrict__ out_l, int N) {
    int tid  = blockIdx.x * blockDim.x + threadIdx.x;
    int wave = tid >> 6, lane = tid & 63, half = lane >> 5, sub = lane & 31;
    int n = wave * 2 + half;
    float aZ = 0.f, aL = 0.f, a0 = 0.f, a1 = 0.f, a2 = 0.f, a3 = 0.f;
    if (n < N) {
        int deg = cnt[n]; if (deg > cap) deg = cap;
        const int* bkt = bucket + (long long)n * cap;
        for (int s = sub; s < deg; s += 32) {
            int e = bkt[s];
            int sn = src[e];
            float l = node_levels[sn];
            float p = __expf(TEMP * edge_w[e] * l);
            float ow, ox, oy, oz;
            hamilton(edge_rel_q[e], node_q[sn], ow, ox, oy, oz);
            aZ += p; aL += p * l; a0 += p * ow; a1 += p * ox; a2 += p * oy; a3 += p * oz;
        }
    }
    for (int m = 16; m; m >>= 1) {
        aZ += __shfl_xor(aZ, m); aL += __shfl_xor(aL, m);
        a0 += __shfl_xor(a0, m); a1 += __shfl_xor(a1, m);
        a2 += __shfl_xor(a2, m); a3 += __shfl_xor(a3, m);
    }
    if (sub == 0 && n < N) {
        const float* rec = side + 6 * (long long)n;
        float l  = node_levels[n];
        float ps = __expf(TEMP * l);
        float Z  = aZ + rec[0] + ps;
        float sl = aL + rec[1] + ps * l;
        float4 q = node_q[n];
        float qw = a0 + rec[2] + ps * q.x;
        float qx = a1 + rec[3] + ps * q.y;
        float qy = a2 + rec[4] + ps * q.z;
        float qz = a3 + rec[5] + ps * q.w;
        float inv = 1.0f / Z;
        qw *= inv; qx *= inv; qy *= inv; qz *= inv;
        float norm = fmaxf(sqrtf(qw*qw + qx*qx + qy*qy + qz*qz), 1e-12f);
        float rn = 1.0f / norm;
        out_q[n] = make_float4(qw * rn, qx * rn, qy * rn, qz * rn);
        out_l[n] = sl * inv;
    }
}

extern "C" void kernel_launch(void* const* d_in, const int* in_sizes, int n_in,
                              void* d_out, int out_size, void* d_ws, size_t ws_size,
                              hipStream_t stream) {
    const float*  node_levels = (const float*)d_in[0];
    const float4* node_q      = (const float4*)d_in[1];
    const float4* edge_rel_q  = (const float4*)d_in[2];
    const float*  edge_w      = (const float*)d_in[3];
    const int*    src         = (const int*)d_in[4];
    const int*    dst         = (const int*)d_in[5];

    const int N = in_sizes[0];
    const int E = in_sizes[3];

    const int B = (N + GSZ - 1) / GSZ;            // coarse buckets
    const int span = (E + NBLK - 1) / NBLK;

    // ws layout: blkhist[B*NBLK] u32 | totals[B] | offsets[B+1] | pad | buckets[E] uint4
    size_t head_elems   = (size_t)B * NBLK + B + (B + 1);
    size_t buckets_byte = (head_elems * 4 + 15) & ~(size_t)15;
    size_t need         = buckets_byte + (size_t)E * 16;

    if (need <= ws_size && B <= BMAX) {
        unsigned* blkhist = (unsigned*)d_ws;
        unsigned* totals  = blkhist + (size_t)B * NBLK;
        unsigned* offsets = totals + B;
        uint4*    buckets = (uint4*)((char*)d_ws + buckets_byte);

        hist_kernel<<<NBLK, HTPB, B * 4, stream>>>(dst, blkhist, E, B, span);
        scan_blocks_kernel<<<B, NBLK, 0, stream>>>(blkhist, totals);
        scan_totals_kernel<<<1, 1024, 0, stream>>>(totals, offsets, B);
        scatter_sort_kernel<<<NBLK, TPB, 0, stream>>>(
            node_levels, node_q, edge_rel_q, edge_w, src, dst,
            blkhist, offsets, buckets, E, B, span);
        gather_sort_kernel<<<B, GTPB, 0, stream>>>(
            node_levels, node_q, offsets, buckets,
            (float4*)d_out, (float*)d_out + 4 * (long long)N, N);
    } else {
        // R3 fallback
        const int tpb = 256;
        size_t cnt_elems  = ((size_t)N + 3) & ~(size_t)3;
        size_t side_elems = 6 * (size_t)N;
        size_t head_bytes = (cnt_elems + side_elems) * 4;
        int cap = 0;
        for (int c : {128, 64}) {
            if (head_bytes + (size_t)N * c * 4 <= ws_size) { cap = c; break; }
        }
        int*   cnt    = (int*)d_ws;
        float* side   = (float*)d_ws + cnt_elems;
        int*   bucket = (int*)d_ws + cnt_elems + side_elems;
        hipMemsetAsync(d_ws, 0, head_bytes, stream);
        scatter_kernel<<<(E + tpb - 1) / tpb, tpb, 0, stream>>>(
            dst, cnt, bucket, cap, node_levels, node_q, edge_rel_q, edge_w, src, side, E);
        int waves  = (N + 1) / 2;
        int blocks = (waves * 64 + tpb - 1) / tpb;
        gather_kernel<<<blocks, tpb, 0, stream>>>(
            node_levels, node_q, edge_rel_q, edge_w, src, cnt, bucket, cap, side,
            (float4*)d_out, (float*)d_out + 4 * (long long)N, N);
    }
}

// Round 7
// 206.879 us; speedup vs baseline: 1.6156x; 1.0137x over previous
//
#include <hip/hip_runtime.h>
#include <hip/hip_fp16.h>

#define TEMP 10.0f
#define TPB 512           // scatter block size
#define HTPB 256          // hist block size
#define NBLK 1024         // hist/scatter grid (all-resident: 4 blocks/CU x 256)
#define SHIFT 9
#define GSZ 512           // nodes per bucket = 1<<SHIFT
#define BMAX 256          // max buckets
#define TILE 1536         // edges per scatter tile = 3 per thread exactly
#define GTPB 1024         // gather block size
#define GT 4096           // records per gather tile (4 regs/thread)

typedef float v2f  __attribute__((ext_vector_type(2)));
typedef float vf4  __attribute__((ext_vector_type(4)));
typedef unsigned uv4 __attribute__((ext_vector_type(4)));

__device__ __forceinline__ int   nt_i (const int* p)   { return __builtin_nontemporal_load(p); }
__device__ __forceinline__ float nt_f (const float* p) { return __builtin_nontemporal_load(p); }
__device__ __forceinline__ float4 nt_f4(const float4* p) {
    vf4 v = __builtin_nontemporal_load((const vf4*)p);
    return make_float4(v.x, v.y, v.z, v.w);
}
__device__ __forceinline__ uint4 nt_u4(const uint4* p) {
    uv4 v = __builtin_nontemporal_load((const uv4*)p);
    uint4 r; r.x = v.x; r.y = v.y; r.z = v.z; r.w = v.w; return r;
}

__device__ __forceinline__ void pk_fadd(float* p, float a, float b) {
#if __has_builtin(__builtin_amdgcn_global_atomic_fadd_v2f32)
    v2f v; v.x = a; v.y = b;
    __builtin_amdgcn_global_atomic_fadd_v2f32(
        (__attribute__((address_space(1))) v2f*)p, v);
#else
    atomicAdd(p, a); atomicAdd(p + 1, b);
#endif
}

__device__ __forceinline__ void hamilton(float4 a, float4 b,
                                         float& ow, float& ox, float& oy, float& oz) {
    ow = a.x*b.x - a.y*b.y - a.z*b.z - a.w*b.w;
    ox = a.x*b.y + a.y*b.x + a.z*b.w - a.w*b.z;
    oy = a.x*b.z - a.y*b.w + a.z*b.x + a.w*b.y;
    oz = a.x*b.w + a.y*b.z - a.z*b.y + a.w*b.x;
}

__device__ __forceinline__ unsigned f2h(float x) {
    return (unsigned)__half_as_ushort(__float2half_rn(x));
}
__device__ __forceinline__ float h2f(unsigned u) {
    return __half2float(__ushort_as_half((unsigned short)(u & 0xFFFFu)));
}

// ---------- pass H: per-block LDS histogram of dst buckets ----------
__global__ void __launch_bounds__(HTPB)
hist_kernel(const int* __restrict__ dst, unsigned* __restrict__ blkhist,
            int E, int B, int span) {
    extern __shared__ unsigned h[];
    for (int i = threadIdx.x; i < B; i += blockDim.x) h[i] = 0;
    __syncthreads();
    int start = blockIdx.x * span;
    int end = start + span; if (end > E) end = E;
    for (int e = start + threadIdx.x; e < end; e += blockDim.x)
        atomicAdd(&h[((unsigned)nt_i(&dst[e])) >> SHIFT], 1u);
    __syncthreads();
    for (int i = threadIdx.x; i < B; i += blockDim.x)
        blkhist[(size_t)i * gridDim.x + blockIdx.x] = h[i];  // bucket-major
}

// ---------- pass P1: exclusive scan across blocks, per bucket ----------
__global__ void __launch_bounds__(1024)
scan_blocks_kernel(unsigned* __restrict__ blkhist, unsigned* __restrict__ totals) {
    __shared__ unsigned s[1024];
    int b = blockIdx.x, t = threadIdx.x, n = blockDim.x;
    unsigned v = blkhist[(size_t)b * n + t];
    s[t] = v; __syncthreads();
    for (int off = 1; off < n; off <<= 1) {
        unsigned add = (t >= off) ? s[t - off] : 0u;
        __syncthreads();
        s[t] += add;
        __syncthreads();
    }
    blkhist[(size_t)b * n + t] = s[t] - v;   // exclusive (local base)
    if (t == n - 1) totals[b] = s[t];
}

// ---------- pass P2: exclusive scan of bucket totals ----------
__global__ void __launch_bounds__(1024)
scan_totals_kernel(const unsigned* __restrict__ totals,
                   unsigned* __restrict__ offsets, int B) {
    __shared__ unsigned s[1024];
    int t = threadIdx.x;
    unsigned v = (t < B) ? totals[t] : 0u;
    s[t] = v; __syncthreads();
    for (int off = 1; off < 1024; off <<= 1) {
        unsigned add = (t >= off) ? s[t - off] : 0u;
        __syncthreads();
        s[t] += add;
        __syncthreads();
    }
    if (t < B) offsets[t] = s[t] - v;
    if (t == B - 1) offsets[B] = s[t];
}

// ---------- pass S: tile-sorted payload placement, ILP-widened ----------
// Latency-throughput bound fix (R7): src/dst prefetched+stashed during hist
// phase; payload issues nl[s]x3 then nq[s]x3 back-to-back (1-deep, 3-wide
// random chain); 4 barriers/tile (gcur folded into scan phase, th-zero folded
// into flush). launch_bounds(512,8) pins VGPR<=64 -> 4 blocks/CU stays.
__global__ void __launch_bounds__(TPB, 8)
scatter_sort_kernel(const float* __restrict__ nl, const float4* __restrict__ nq,
                    const float4* __restrict__ erq, const float* __restrict__ ew,
                    const int* __restrict__ src, const int* __restrict__ dst,
                    const unsigned* __restrict__ blkhist,
                    const unsigned* __restrict__ offsets,
                    uint4* __restrict__ buckets,
                    int E, int B, int span) {
    __shared__ uint4    stage[TILE];     // 24 KB
    __shared__ unsigned gslot[TILE];     //  6 KB
    __shared__ unsigned gcur[BMAX];      //  1 KB each below
    __shared__ unsigned th[BMAX];
    __shared__ unsigned basec[BMAX];
    __shared__ unsigned curt[BMAX];
    __shared__ unsigned gbase[BMAX];

    int blk = blockIdx.x, nb = gridDim.x, tid = threadIdx.x;
    for (int b = tid; b < B; b += TPB) {
        gcur[b] = offsets[b] + blkhist[(size_t)b * nb + blk];
        th[b] = 0;
    }
    int start = blk * span;
    int end = start + span; if (end > E) end = E;
    __syncthreads();

    for (int ts = start; ts < end; ts += TILE) {
        int tE = end - ts; if (tE > TILE) tE = TILE;

        // phase 1: histogram + stash src/dst in registers (th pre-zeroed)
        int s_[3]; unsigned d_[3];
        #pragma unroll
        for (int j = 0; j < 3; ++j) {
            int k = tid + j * TPB;
            if (k < tE) {
                d_[j] = (unsigned)nt_i(&dst[ts + k]);
                s_[j] = nt_i(&src[ts + k]);
                atomicAdd(&th[d_[j] >> SHIFT], 1u);
            }
        }
        __syncthreads();

        // phase 2: wave0 scans tile hist; threads >=256 snapshot gbase, advance gcur
        if (tid < 64) {
            int lane = tid;
            unsigned vals[4];
            unsigned tot = 0;
            #pragma unroll
            for (int c = 0; c < 4; ++c) {
                int i = lane * 4 + c;
                vals[c] = (i < B) ? th[i] : 0u;
                tot += vals[c];
            }
            unsigned inc = tot;
            #pragma unroll
            for (int off = 1; off < 64; off <<= 1) {
                unsigned up = __shfl_up(inc, off);
                if (lane >= off) inc += up;
            }
            unsigned run = inc - tot;     // exclusive
            #pragma unroll
            for (int c = 0; c < 4; ++c) {
                int i = lane * 4 + c;
                if (i < B) { basec[i] = run; curt[i] = run; }
                run += vals[c];
            }
        } else if (tid >= 256) {
            for (int b = tid - 256; b < B; b += TPB - 256) {
                gbase[b] = gcur[b];
                gcur[b] += th[b];
            }
        }
        __syncthreads();

        // phase 3: payload — wide random loads first, then compute+place
        float l_[3]; float4 q_[3];
        #pragma unroll
        for (int j = 0; j < 3; ++j) { int k = tid + j * TPB; if (k < tE) l_[j] = nl[s_[j]]; }
        #pragma unroll
        for (int j = 0; j < 3; ++j) { int k = tid + j * TPB; if (k < tE) q_[j] = nq[s_[j]]; }
        #pragma unroll
        for (int j = 0; j < 3; ++j) {
            int k = tid + j * TPB;
            if (k < tE) {
                float p = __expf(TEMP * nt_f(&ew[ts + k]) * l_[j]);
                float ow, ox, oy, oz;
                hamilton(nt_f4(&erq[ts + k]), q_[j], ow, ox, oy, oz);
                unsigned b = d_[j] >> SHIFT;
                unsigned pos = atomicAdd(&curt[b], 1u);
                uint4 pk;
                pk.x = (d_[j] & (GSZ - 1)) | (f2h(p) << 16);
                pk.y = f2h(p * l_[j]) | (f2h(p * ow) << 16);
                pk.z = f2h(p * ox) | (f2h(p * oy) << 16);
                pk.w = f2h(p * oz);
                stage[pos] = pk;
                gslot[pos] = gbase[b] + (pos - basec[b]);
            }
        }
        __syncthreads();

        // phase 4: flush in sorted order + zero th for next tile
        for (int k = tid; k < tE; k += TPB)
            buckets[gslot[k]] = stage[k];
        for (int b = tid; b < B; b += TPB) th[b] = 0;
        __syncthreads();
    }
}

// ---------- pass G: LDS counting sort per tile + register segmented reduce ----------
__global__ void __launch_bounds__(GTPB)
gather_sort_kernel(const float* __restrict__ nl, const float4* __restrict__ nq,
                   const unsigned* __restrict__ offsets,
                   const uint4* __restrict__ buckets,
                   float4* __restrict__ out_q, float* __restrict__ out_l, int N) {
    __shared__ unsigned s0a[GT];        // 16 KB  p | poz<<16
    __shared__ unsigned s1a[GT];        // 16 KB  pl | pow<<16
    __shared__ unsigned s2a[GT];        // 16 KB  pox | poy<<16
    __shared__ unsigned cnt[GSZ];       //  2 KB  count, then cursor
    __shared__ unsigned base[GSZ + 1];  //  2 KB  run starts

    int b = blockIdx.x, tid = threadIdx.x;
    unsigned q0 = offsets[b], q1 = offsets[b + 1];
    int M = (int)(q1 - q0);

    float accZ = 0.f, accL = 0.f, accW = 0.f, accX = 0.f, accY = 0.f, accV = 0.f;

    for (int t0 = 0; t0 < M; t0 += GT) {
        int tGT = M - t0; if (tGT > GT) tGT = GT;
        for (int i = tid; i < GSZ; i += GTPB) cnt[i] = 0;
        __syncthreads();

        // load tile into registers + u32 count histogram
        uint4 pk0, pk1, pk2, pk3;
        int i0 = tid, i1 = tid + GTPB, i2 = tid + 2 * GTPB, i3 = tid + 3 * GTPB;
        if (i0 < tGT) { pk0 = nt_u4(&buckets[q0 + t0 + i0]); atomicAdd(&cnt[pk0.x & (GSZ-1)], 1u); }
        if (i1 < tGT) { pk1 = nt_u4(&buckets[q0 + t0 + i1]); atomicAdd(&cnt[pk1.x & (GSZ-1)], 1u); }
        if (i2 < tGT) { pk2 = nt_u4(&buckets[q0 + t0 + i2]); atomicAdd(&cnt[pk2.x & (GSZ-1)], 1u); }
        if (i3 < tGT) { pk3 = nt_u4(&buckets[q0 + t0 + i3]); atomicAdd(&cnt[pk3.x & (GSZ-1)], 1u); }
        __syncthreads();

        // wave-0 exclusive scan of 512 counts (8 per lane + shfl)
        if (tid < 64) {
            unsigned vals[8], tot = 0;
            #pragma unroll
            for (int c = 0; c < 8; ++c) { vals[c] = cnt[tid * 8 + c]; tot += vals[c]; }
            unsigned inc = tot;
            #pragma unroll
            for (int off = 1; off < 64; off <<= 1) {
                unsigned up = __shfl_up(inc, off);
                if (tid >= off) inc += up;
            }
            unsigned run = inc - tot;     // exclusive
            #pragma unroll
            for (int c = 0; c < 8; ++c) {
                base[tid * 8 + c] = run;
                cnt[tid * 8 + c]  = run;  // becomes cursor
                run += vals[c];
            }
            if (tid == 63) base[GSZ] = run;   // = tGT
        }
        __syncthreads();

        // place records at sorted positions (u32 cursor atomic)
        if (i0 < tGT) { unsigned p = atomicAdd(&cnt[pk0.x & (GSZ-1)], 1u);
                        s0a[p] = (pk0.x >> 16) | (pk0.w << 16); s1a[p] = pk0.y; s2a[p] = pk0.z; }
        if (i1 < tGT) { unsigned p = atomicAdd(&cnt[pk1.x & (GSZ-1)], 1u);
                        s0a[p] = (pk1.x >> 16) | (pk1.w << 16); s1a[p] = pk1.y; s2a[p] = pk1.z; }
        if (i2 < tGT) { unsigned p = atomicAdd(&cnt[pk2.x & (GSZ-1)], 1u);
                        s0a[p] = (pk2.x >> 16) | (pk2.w << 16); s1a[p] = pk2.y; s2a[p] = pk2.z; }
        if (i3 < tGT) { unsigned p = atomicAdd(&cnt[pk3.x & (GSZ-1)], 1u);
                        s0a[p] = (pk3.x >> 16) | (pk3.w << 16); s1a[p] = pk3.y; s2a[p] = pk3.z; }
        __syncthreads();

        // segmented reduce: thread j owns node j, contiguous LDS run
        if (tid < GSZ) {
            unsigned lo = base[tid], hi = base[tid + 1];
            for (unsigned p = lo; p < hi; ++p) {
                unsigned a = s0a[p], d = s1a[p], e = s2a[p];
                accZ += h2f(a);        accV += h2f(a >> 16);
                accL += h2f(d);        accW += h2f(d >> 16);
                accX += h2f(e);        accY += h2f(e >> 16);
            }
        }
        __syncthreads();
    }

    // fused finalize: self term + normalize
    if (tid < GSZ) {
        int n = b * GSZ + tid;
        if (n < N) {
            float l  = nl[n];
            float ps = __expf(TEMP * l);
            float Z  = accZ + ps;
            float sl = accL + ps * l;
            float4 q = nq[n];
            float qw = accW + ps * q.x;
            float qx = accX + ps * q.y;
            float qy = accY + ps * q.z;
            float qz = accV + ps * q.w;
            float inv = 1.0f / Z;
            qw *= inv; qx *= inv; qy *= inv; qz *= inv;
            float norm = fmaxf(sqrtf(qw*qw + qx*qx + qy*qy + qz*qz), 1e-12f);
            float rn = 1.0f / norm;
            out_q[n] = make_float4(qw * rn, qx * rn, qy * rn, qz * rn);
            out_l[n] = sl * inv;
        }
    }
}

// ---------------- fallback path (R3) ----------------
__global__ void __launch_bounds__(256)
scatter_kernel(const int* __restrict__ dst, int* __restrict__ cnt,
               int* __restrict__ bucket, int cap,
               const float* __restrict__ node_levels, const float4* __restrict__ node_q,
               const float4* __restrict__ edge_rel_q, const float* __restrict__ edge_w,
               const int* __restrict__ src, float* __restrict__ side, int E) {
    int e = blockIdx.x * blockDim.x + threadIdx.x;
    if (e >= E) return;
    int d = dst[e];
    int slot = atomicAdd(&cnt[d], 1);
    if (slot < cap) {
        bucket[(long long)d * cap + slot] = e;
    } else {
        int s = src[e];
        float l = node_levels[s];
        float p = __expf(TEMP * edge_w[e] * l);
        float ow, ox, oy, oz;
        hamilton(edge_rel_q[e], node_q[s], ow, ox, oy, oz);
        float* rec = side + 6 * (long long)d;
        pk_fadd(rec + 0, p,      p * l);
        pk_fadd(rec + 2, p * ow, p * ox);
        pk_fadd(rec + 4, p * oy, p * oz);
    }
}

__global__ void __launch_bounds__(256)
gather_kernel(const float* __restrict__ node_levels, const float4* __restrict__ node_q,
              const float4* __restrict__ edge_rel_q, const float* __restrict__ edge_w,
              const int* __restrict__ src, const int* __restrict__ cnt,
              const int* __restrict__ bucket, int cap, const float* __restrict__ side,
              float4* __restrict__ out_q, float* __restrict__ out_l, int N) {
    int tid  = blockIdx.x * blockDim.x + threadIdx.x;
    int wave = tid >> 6, lane = tid & 63, half = lane >> 5, sub = lane & 31;
    int n = wave * 2 + half;
    float aZ = 0.f, aL = 0.f, a0 = 0.f, a1 = 0.f, a2 = 0.f, a3 = 0.f;
    if (n < N) {
        int deg = cnt[n]; if (deg > cap) deg = cap;
        const int* bkt = bucket + (long long)n * cap;
        for (int s = sub; s < deg; s += 32) {
            int e = bkt[s];
            int sn = src[e];
            float l = node_levels[sn];
            float p = __expf(TEMP * edge_w[e] * l);
            float ow, ox, oy, oz;
            hamilton(edge_rel_q[e], node_q[sn], ow, ox, oy, oz);
            aZ += p; aL += p * l; a0 += p * ow; a1 += p * ox; a2 += p * oy; a3 += p * oz;
        }
    }
    for (int m = 16; m; m >>= 1) {
        aZ += __shfl_xor(aZ, m); aL += __shfl_xor(aL, m);
        a0 += __shfl_xor(a0, m); a1 += __shfl_xor(a1, m);
        a2 += __shfl_xor(a2, m); a3 += __shfl_xor(a3, m);
    }
    if (sub == 0 && n < N) {
        const float* rec = side + 6 * (long long)n;
        float l  = node_levels[n];
        float ps = __expf(TEMP * l);
        float Z  = aZ + rec[0] + ps;
        float sl = aL + rec[1] + ps * l;
        float4 q = node_q[n];
        float qw = a0 + rec[2] + ps * q.x;
        float qx = a1 + rec[3] + ps * q.y;
        float qy = a2 + rec[4] + ps * q.z;
        float qz = a3 + rec[5] + ps * q.w;
        float inv = 1.0f / Z;
        qw *= inv; qx *= inv; qy *= inv; qz *= inv;
        float norm = fmaxf(sqrtf(qw*qw + qx*qx + qy*qy + qz*qz), 1e-12f);
        float rn = 1.0f / norm;
        out_q[n] = make_float4(qw * rn, qx * rn, qy * rn, qz * rn);
        out_l[n] = sl * inv;
    }
}

extern "C" void kernel_launch(void* const* d_in, const int* in_sizes, int n_in,
                              void* d_out, int out_size, void* d_ws, size_t ws_size,
                              hipStream_t stream) {
    const float*  node_levels = (const float*)d_in[0];
    const float4* node_q      = (const float4*)d_in[1];
    const float4* edge_rel_q  = (const float4*)d_in[2];
    const float*  edge_w      = (const float*)d_in[3];
    const int*    src         = (const int*)d_in[4];
    const int*    dst         = (const int*)d_in[5];

    const int N = in_sizes[0];
    const int E = in_sizes[3];

    const int B = (N + GSZ - 1) / GSZ;            // coarse buckets
    const int span = (E + NBLK - 1) / NBLK;

    // ws layout: blkhist[B*NBLK] u32 | totals[B] | offsets[B+1] | pad | buckets[E] uint4
    size_t head_elems   = (size_t)B * NBLK + B + (B + 1);
    size_t buckets_byte = (head_elems * 4 + 15) & ~(size_t)15;
    size_t need         = buckets_byte + (size_t)E * 16;

    if (need <= ws_size && B <= BMAX) {
        unsigned* blkhist = (unsigned*)d_ws;
        unsigned* totals  = blkhist + (size_t)B * NBLK;
        unsigned* offsets = totals + B;
        uint4*    buckets = (uint4*)((char*)d_ws + buckets_byte);

        hist_kernel<<<NBLK, HTPB, B * 4, stream>>>(dst, blkhist, E, B, span);
        scan_blocks_kernel<<<B, NBLK, 0, stream>>>(blkhist, totals);
        scan_totals_kernel<<<1, 1024, 0, stream>>>(totals, offsets, B);
        scatter_sort_kernel<<<NBLK, TPB, 0, stream>>>(
            node_levels, node_q, edge_rel_q, edge_w, src, dst,
            blkhist, offsets, buckets, E, B, span);
        gather_sort_kernel<<<B, GTPB, 0, stream>>>(
            node_levels, node_q, offsets, buckets,
            (float4*)d_out, (float*)d_out + 4 * (long long)N, N);
    } else {
        // R3 fallback
        const int tpb = 256;
        size_t cnt_elems  = ((size_t)N + 3) & ~(size_t)3;
        size_t side_elems = 6 * (size_t)N;
        size_t head_bytes = (cnt_elems + side_elems) * 4;
        int cap = 0;
        for (int c : {128, 64}) {
            if (head_bytes + (size_t)N * c * 4 <= ws_size) { cap = c; break; }
        }
        int*   cnt    = (int*)d_ws;
        float* side   = (float*)d_ws + cnt_elems;
        int*   bucket = (int*)d_ws + cnt_elems + side_elems;
        hipMemsetAsync(d_ws, 0, head_bytes, stream);
        scatter_kernel<<<(E + tpb - 1) / tpb, tpb, 0, stream>>>(
            dst, cnt, bucket, cap, node_levels, node_q, edge_rel_q, edge_w, src, side, E);
        int waves  = (N + 1) / 2;
        int blocks = (waves * 64 + tpb - 1) / tpb;
        gather_kernel<<<blocks, tpb, 0, stream>>>(
            node_levels, node_q, edge_rel_q, edge_w, src, cnt, bucket, cap, side,
            (float4*)d_out, (float*)d_out + 4 * (long long)N, N);
    }
}

// Round 8
// 197.253 us; speedup vs baseline: 1.6944x; 1.0488x over previous
//
#include <hip/hip_runtime.h>
#include <hip/hip_fp16.h>

#define TEMP 10.0f
#define TPB 512           // scatter block size
#define HTPB 256          // hist block size
#define NBLK 1024         // hist/scatter grid (all-resident: 4 blocks/CU x 256)
#define SHIFT 9
#define GSZ 512           // nodes per bucket = 1<<SHIFT
#define BMAX 256          // max buckets
#define TILE 1568         // edges per scatter tile -> span 3125 = 2 tiles (1568+1557)
#define GTPB 1024         // gather block size
#define GT 4096           // records per gather tile (4 regs/thread)

typedef float v2f  __attribute__((ext_vector_type(2)));
typedef float vf4  __attribute__((ext_vector_type(4)));
typedef unsigned uv4 __attribute__((ext_vector_type(4)));

__device__ __forceinline__ int   nt_i (const int* p)   { return __builtin_nontemporal_load(p); }
__device__ __forceinline__ float nt_f (const float* p) { return __builtin_nontemporal_load(p); }
__device__ __forceinline__ float4 nt_f4(const float4* p) {
    vf4 v = __builtin_nontemporal_load((const vf4*)p);
    return make_float4(v.x, v.y, v.z, v.w);
}
__device__ __forceinline__ uint4 nt_u4(const uint4* p) {
    uv4 v = __builtin_nontemporal_load((const uv4*)p);
    uint4 r; r.x = v.x; r.y = v.y; r.z = v.z; r.w = v.w; return r;
}

__device__ __forceinline__ void pk_fadd(float* p, float a, float b) {
#if __has_builtin(__builtin_amdgcn_global_atomic_fadd_v2f32)
    v2f v; v.x = a; v.y = b;
    __builtin_amdgcn_global_atomic_fadd_v2f32(
        (__attribute__((address_space(1))) v2f*)p, v);
#else
    atomicAdd(p, a); atomicAdd(p + 1, b);
#endif
}

__device__ __forceinline__ void hamilton(float4 a, float4 b,
                                         float& ow, float& ox, float& oy, float& oz) {
    ow = a.x*b.x - a.y*b.y - a.z*b.z - a.w*b.w;
    ox = a.x*b.y + a.y*b.x + a.z*b.w - a.w*b.z;
    oy = a.x*b.z - a.y*b.w + a.z*b.x + a.w*b.y;
    oz = a.x*b.w + a.y*b.z - a.z*b.y + a.w*b.x;
}

__device__ __forceinline__ unsigned f2h(float x) {
    return (unsigned)__half_as_ushort(__float2half_rn(x));
}
__device__ __forceinline__ float h2f(unsigned u) {
    return __half2float(__ushort_as_half((unsigned short)(u & 0xFFFFu)));
}

// ---------- pass N: pack node table to ONE 16B line per random access ----------
// pack[n] = {copysign(l, qz), qw, qx, qy}; qz recovered from unit-norm.
__global__ void __launch_bounds__(256)
pack_kernel(const float* __restrict__ nl, const float4* __restrict__ nq,
            float4* __restrict__ pack, int N) {
    int n = blockIdx.x * 256 + threadIdx.x;
    if (n >= N) return;
    float l = nl[n];
    float4 q = nq[n];                       // (w,x,y,z)
    pack[n] = make_float4(copysignf(l, q.w), q.x, q.y, q.z);
}

// ---------- pass H: per-block LDS histogram of dst buckets ----------
__global__ void __launch_bounds__(HTPB)
hist_kernel(const int* __restrict__ dst, unsigned* __restrict__ blkhist,
            int E, int B, int span) {
    extern __shared__ unsigned h[];
    for (int i = threadIdx.x; i < B; i += blockDim.x) h[i] = 0;
    __syncthreads();
    int start = blockIdx.x * span;
    int end = start + span; if (end > E) end = E;
    for (int e = start + threadIdx.x; e < end; e += blockDim.x)
        atomicAdd(&h[((unsigned)nt_i(&dst[e])) >> SHIFT], 1u);
    __syncthreads();
    for (int i = threadIdx.x; i < B; i += blockDim.x)
        blkhist[(size_t)i * gridDim.x + blockIdx.x] = h[i];  // bucket-major
}

// ---------- pass P1: exclusive scan across blocks, per bucket ----------
__global__ void __launch_bounds__(1024)
scan_blocks_kernel(unsigned* __restrict__ blkhist, unsigned* __restrict__ totals) {
    __shared__ unsigned s[1024];
    int b = blockIdx.x, t = threadIdx.x, n = blockDim.x;
    unsigned v = blkhist[(size_t)b * n + t];
    s[t] = v; __syncthreads();
    for (int off = 1; off < n; off <<= 1) {
        unsigned add = (t >= off) ? s[t - off] : 0u;
        __syncthreads();
        s[t] += add;
        __syncthreads();
    }
    blkhist[(size_t)b * n + t] = s[t] - v;   // exclusive (local base)
    if (t == n - 1) totals[b] = s[t];
}

// ---------- pass P2: exclusive scan of bucket totals ----------
__global__ void __launch_bounds__(1024)
scan_totals_kernel(const unsigned* __restrict__ totals,
                   unsigned* __restrict__ offsets, int B) {
    __shared__ unsigned s[1024];
    int t = threadIdx.x;
    unsigned v = (t < B) ? totals[t] : 0u;
    s[t] = v; __syncthreads();
    for (int off = 1; off < 1024; off <<= 1) {
        unsigned add = (t >= off) ? s[t - off] : 0u;
        __syncthreads();
        s[t] += add;
        __syncthreads();
    }
    if (t < B) offsets[t] = s[t] - v;
    if (t == B - 1) offsets[B] = s[t];
}

// ---------- pass S: tile-sorted payload placement ----------
// MSHR fix (R8): the per-edge random read is ONE aligned 16B load from pack[]
// (one 64B line) instead of nl[s] + nq[s] (two lines). 2 tiles/block, 4
// barriers/tile, 4 blocks/CU at 36.5KB LDS.
__global__ void __launch_bounds__(TPB, 8)
scatter_sort_kernel(const float4* __restrict__ pack,
                    const float4* __restrict__ erq, const float* __restrict__ ew,
                    const int* __restrict__ src, const int* __restrict__ dst,
                    const unsigned* __restrict__ blkhist,
                    const unsigned* __restrict__ offsets,
                    uint4* __restrict__ buckets,
                    int E, int B, int span) {
    __shared__ uint4    stage[TILE];     // 24.5 KB
    __shared__ unsigned gslot[TILE];     //  6.1 KB
    __shared__ unsigned gcur[BMAX];      //  1 KB each below
    __shared__ unsigned th[BMAX];
    __shared__ unsigned basec[BMAX];
    __shared__ unsigned curt[BMAX];
    __shared__ unsigned gbase[BMAX];

    int blk = blockIdx.x, nb = gridDim.x, tid = threadIdx.x;
    for (int b = tid; b < B; b += TPB) {
        gcur[b] = offsets[b] + blkhist[(size_t)b * nb + blk];
        th[b] = 0;
    }
    int start = blk * span;
    int end = start + span; if (end > E) end = E;
    __syncthreads();

    for (int ts = start; ts < end; ts += TILE) {
        int tE = end - ts; if (tE > TILE) tE = TILE;

        // phase 1: histogram + stash src/dst in registers (th pre-zeroed)
        int s_[4]; unsigned d_[4];
        #pragma unroll
        for (int j = 0; j < 4; ++j) {
            int k = tid + j * TPB;
            if (k < tE) {
                d_[j] = (unsigned)nt_i(&dst[ts + k]);
                s_[j] = nt_i(&src[ts + k]);
                atomicAdd(&th[d_[j] >> SHIFT], 1u);
            }
        }
        __syncthreads();

        // phase 2: wave0 scans tile hist; threads >=256 snapshot gbase, advance gcur
        if (tid < 64) {
            int lane = tid;
            unsigned vals[4];
            unsigned tot = 0;
            #pragma unroll
            for (int c = 0; c < 4; ++c) {
                int i = lane * 4 + c;
                vals[c] = (i < B) ? th[i] : 0u;
                tot += vals[c];
            }
            unsigned inc = tot;
            #pragma unroll
            for (int off = 1; off < 64; off <<= 1) {
                unsigned up = __shfl_up(inc, off);
                if (lane >= off) inc += up;
            }
            unsigned run = inc - tot;     // exclusive
            #pragma unroll
            for (int c = 0; c < 4; ++c) {
                int i = lane * 4 + c;
                if (i < B) { basec[i] = run; curt[i] = run; }
                run += vals[c];
            }
        } else if (tid >= 256) {
            for (int b = tid - 256; b < B; b += TPB - 256) {
                gbase[b] = gcur[b];
                gcur[b] += th[b];
            }
        }
        __syncthreads();

        // phase 3: ONE wide random 16B load per edge, then compute+place
        float4 pq_[4];
        #pragma unroll
        for (int j = 0; j < 4; ++j) { int k = tid + j * TPB; if (k < tE) pq_[j] = pack[s_[j]]; }
        #pragma unroll
        for (int j = 0; j < 4; ++j) {
            int k = tid + j * TPB;
            if (k < tE) {
                float l  = fabsf(pq_[j].x);
                float qw = pq_[j].y, qx = pq_[j].z, qy = pq_[j].w;
                float qz = copysignf(sqrtf(fmaxf(0.f, 1.f - qw*qw - qx*qx - qy*qy)),
                                     pq_[j].x);
                float p = __expf(TEMP * nt_f(&ew[ts + k]) * l);
                float ow, ox, oy, oz;
                hamilton(nt_f4(&erq[ts + k]), make_float4(qw, qx, qy, qz), ow, ox, oy, oz);
                unsigned b = d_[j] >> SHIFT;
                unsigned pos = atomicAdd(&curt[b], 1u);
                uint4 pk;
                pk.x = (d_[j] & (GSZ - 1)) | (f2h(p) << 16);
                pk.y = f2h(p * l) | (f2h(p * ow) << 16);
                pk.z = f2h(p * ox) | (f2h(p * oy) << 16);
                pk.w = f2h(p * oz);
                stage[pos] = pk;
                gslot[pos] = gbase[b] + (pos - basec[b]);
            }
        }
        __syncthreads();

        // phase 4: flush in sorted order + zero th for next tile
        for (int k = tid; k < tE; k += TPB)
            buckets[gslot[k]] = stage[k];
        for (int b = tid; b < B; b += TPB) th[b] = 0;
        __syncthreads();
    }
}

// ---------- pass G: LDS counting sort per tile + register segmented reduce ----------
__global__ void __launch_bounds__(GTPB)
gather_sort_kernel(const float* __restrict__ nl, const float4* __restrict__ nq,
                   const unsigned* __restrict__ offsets,
                   const uint4* __restrict__ buckets,
                   float4* __restrict__ out_q, float* __restrict__ out_l, int N) {
    __shared__ unsigned s0a[GT];        // 16 KB  p | poz<<16
    __shared__ unsigned s1a[GT];        // 16 KB  pl | pow<<16
    __shared__ unsigned s2a[GT];        // 16 KB  pox | poy<<16
    __shared__ unsigned cnt[GSZ];       //  2 KB  count, then cursor
    __shared__ unsigned base[GSZ + 1];  //  2 KB  run starts

    int b = blockIdx.x, tid = threadIdx.x;
    unsigned q0 = offsets[b], q1 = offsets[b + 1];
    int M = (int)(q1 - q0);

    float accZ = 0.f, accL = 0.f, accW = 0.f, accX = 0.f, accY = 0.f, accV = 0.f;

    for (int t0 = 0; t0 < M; t0 += GT) {
        int tGT = M - t0; if (tGT > GT) tGT = GT;
        for (int i = tid; i < GSZ; i += GTPB) cnt[i] = 0;
        __syncthreads();

        // load tile into registers + u32 count histogram
        uint4 pk0, pk1, pk2, pk3;
        int i0 = tid, i1 = tid + GTPB, i2 = tid + 2 * GTPB, i3 = tid + 3 * GTPB;
        if (i0 < tGT) { pk0 = nt_u4(&buckets[q0 + t0 + i0]); atomicAdd(&cnt[pk0.x & (GSZ-1)], 1u); }
        if (i1 < tGT) { pk1 = nt_u4(&buckets[q0 + t0 + i1]); atomicAdd(&cnt[pk1.x & (GSZ-1)], 1u); }
        if (i2 < tGT) { pk2 = nt_u4(&buckets[q0 + t0 + i2]); atomicAdd(&cnt[pk2.x & (GSZ-1)], 1u); }
        if (i3 < tGT) { pk3 = nt_u4(&buckets[q0 + t0 + i3]); atomicAdd(&cnt[pk3.x & (GSZ-1)], 1u); }
        __syncthreads();

        // wave-0 exclusive scan of 512 counts (8 per lane + shfl)
        if (tid < 64) {
            unsigned vals[8], tot = 0;
            #pragma unroll
            for (int c = 0; c < 8; ++c) { vals[c] = cnt[tid * 8 + c]; tot += vals[c]; }
            unsigned inc = tot;
            #pragma unroll
            for (int off = 1; off < 64; off <<= 1) {
                unsigned up = __shfl_up(inc, off);
                if (tid >= off) inc += up;
            }
            unsigned run = inc - tot;     // exclusive
            #pragma unroll
            for (int c = 0; c < 8; ++c) {
                base[tid * 8 + c] = run;
                cnt[tid * 8 + c]  = run;  // becomes cursor
                run += vals[c];
            }
            if (tid == 63) base[GSZ] = run;   // = tGT
        }
        __syncthreads();

        // place records at sorted positions (u32 cursor atomic)
        if (i0 < tGT) { unsigned p = atomicAdd(&cnt[pk0.x & (GSZ-1)], 1u);
                        s0a[p] = (pk0.x >> 16) | (pk0.w << 16); s1a[p] = pk0.y; s2a[p] = pk0.z; }
        if (i1 < tGT) { unsigned p = atomicAdd(&cnt[pk1.x & (GSZ-1)], 1u);
                        s0a[p] = (pk1.x >> 16) | (pk1.w << 16); s1a[p] = pk1.y; s2a[p] = pk1.z; }
        if (i2 < tGT) { unsigned p = atomicAdd(&cnt[pk2.x & (GSZ-1)], 1u);
                        s0a[p] = (pk2.x >> 16) | (pk2.w << 16); s1a[p] = pk2.y; s2a[p] = pk2.z; }
        if (i3 < tGT) { unsigned p = atomicAdd(&cnt[pk3.x & (GSZ-1)], 1u);
                        s0a[p] = (pk3.x >> 16) | (pk3.w << 16); s1a[p] = pk3.y; s2a[p] = pk3.z; }
        __syncthreads();

        // segmented reduce: thread j owns node j, contiguous LDS run
        if (tid < GSZ) {
            unsigned lo = base[tid], hi = base[tid + 1];
            for (unsigned p = lo; p < hi; ++p) {
                unsigned a = s0a[p], d = s1a[p], e = s2a[p];
                accZ += h2f(a);        accV += h2f(a >> 16);
                accL += h2f(d);        accW += h2f(d >> 16);
                accX += h2f(e);        accY += h2f(e >> 16);
            }
        }
        __syncthreads();
    }

    // fused finalize: self term + normalize
    if (tid < GSZ) {
        int n = b * GSZ + tid;
        if (n < N) {
            float l  = nl[n];
            float ps = __expf(TEMP * l);
            float Z  = accZ + ps;
            float sl = accL + ps * l;
            float4 q = nq[n];
            float qw = accW + ps * q.x;
            float qx = accX + ps * q.y;
            float qy = accY + ps * q.z;
            float qz = accV + ps * q.w;
            float inv = 1.0f / Z;
            qw *= inv; qx *= inv; qy *= inv; qz *= inv;
            float norm = fmaxf(sqrtf(qw*qw + qx*qx + qy*qy + qz*qz), 1e-12f);
            float rn = 1.0f / norm;
            out_q[n] = make_float4(qw * rn, qx * rn, qy * rn, qz * rn);
            out_l[n] = sl * inv;
        }
    }
}

// ---------------- fallback path (R3) ----------------
__global__ void __launch_bounds__(256)
scatter_kernel(const int* __restrict__ dst, int* __restrict__ cnt,
               int* __restrict__ bucket, int cap,
               const float* __restrict__ node_levels, const float4* __restrict__ node_q,
               const float4* __restrict__ edge_rel_q, const float* __restrict__ edge_w,
               const int* __restrict__ src, float* __restrict__ side, int E) {
    int e = blockIdx.x * blockDim.x + threadIdx.x;
    if (e >= E) return;
    int d = dst[e];
    int slot = atomicAdd(&cnt[d], 1);
    if (slot < cap) {
        bucket[(long long)d * cap + slot] = e;
    } else {
        int s = src[e];
        float l = node_levels[s];
        float p = __expf(TEMP * edge_w[e] * l);
        float ow, ox, oy, oz;
        hamilton(edge_rel_q[e], node_q[s], ow, ox, oy, oz);
        float* rec = side + 6 * (long long)d;
        pk_fadd(rec + 0, p,      p * l);
        pk_fadd(rec + 2, p * ow, p * ox);
        pk_fadd(rec + 4, p * oy, p * oz);
    }
}

__global__ void __launch_bounds__(256)
gather_kernel(const float* __restrict__ node_levels, const float4* __restrict__ node_q,
              const float4* __restrict__ edge_rel_q, const float* __restrict__ edge_w,
              const int* __restrict__ src, const int* __restrict__ cnt,
              const int* __restrict__ bucket, int cap, const float* __restrict__ side,
              float4* __restrict__ out_q, float* __restrict__ out_l, int N) {
    int tid  = blockIdx.x * blockDim.x + threadIdx.x;
    int wave = tid >> 6, lane = tid & 63, half = lane >> 5, sub = lane & 31;
    int n = wave * 2 + half;
    float aZ = 0.f, aL = 0.f, a0 = 0.f, a1 = 0.f, a2 = 0.f, a3 = 0.f;
    if (n < N) {
        int deg = cnt[n]; if (deg > cap) deg = cap;
        const int* bkt = bucket + (long long)n * cap;
        for (int s = sub; s < deg; s += 32) {
            int e = bkt[s];
            int sn = src[e];
            float l = node_levels[sn];
            float p = __expf(TEMP * edge_w[e] * l);
            float ow, ox, oy, oz;
            hamilton(edge_rel_q[e], node_q[sn], ow, ox, oy, oz);
            aZ += p; aL += p * l; a0 += p * ow; a1 += p * ox; a2 += p * oy; a3 += p * oz;
        }
    }
    for (int m = 16; m; m >>= 1) {
        aZ += __shfl_xor(aZ, m); aL += __shfl_xor(aL, m);
        a0 += __shfl_xor(a0, m); a1 += __shfl_xor(a1, m);
        a2 += __shfl_xor(a2, m); a3 += __shfl_xor(a3, m);
    }
    if (sub == 0 && n < N) {
        const float* rec = side + 6 * (long long)n;
        float l  = node_levels[n];
        float ps = __expf(TEMP * l);
        float Z  = aZ + rec[0] + ps;
        float sl = aL + rec[1] + ps * l;
        float4 q = node_q[n];
        float qw = a0 + rec[2] + ps * q.x;
        float qx = a1 + rec[3] + ps * q.y;
        float qy = a2 + rec[4] + ps * q.z;
        float qz = a3 + rec[5] + ps * q.w;
        float inv = 1.0f / Z;
        qw *= inv; qx *= inv; qy *= inv; qz *= inv;
        float norm = fmaxf(sqrtf(qw*qw + qx*qx + qy*qy + qz*qz), 1e-12f);
        float rn = 1.0f / norm;
        out_q[n] = make_float4(qw * rn, qx * rn, qy * rn, qz * rn);
        out_l[n] = sl * inv;
    }
}

extern "C" void kernel_launch(void* const* d_in, const int* in_sizes, int n_in,
                              void* d_out, int out_size, void* d_ws, size_t ws_size,
                              hipStream_t stream) {
    const float*  node_levels = (const float*)d_in[0];
    const float4* node_q      = (const float4*)d_in[1];
    const float4* edge_rel_q  = (const float4*)d_in[2];
    const float*  edge_w      = (const float*)d_in[3];
    const int*    src         = (const int*)d_in[4];
    const int*    dst         = (const int*)d_in[5];

    const int N = in_sizes[0];
    const int E = in_sizes[3];

    const int B = (N + GSZ - 1) / GSZ;            // coarse buckets
    const int span = (E + NBLK - 1) / NBLK;

    // ws layout: blkhist[B*NBLK] u32 | totals[B] | offsets[B+1] | pad |
    //            buckets[E] uint4 | pack[N] float4
    size_t head_elems   = (size_t)B * NBLK + B + (B + 1);
    size_t buckets_byte = (head_elems * 4 + 15) & ~(size_t)15;
    size_t pack_byte    = buckets_byte + (size_t)E * 16;
    size_t need         = pack_byte + (size_t)N * 16;

    if (need <= ws_size && B <= BMAX) {
        unsigned* blkhist = (unsigned*)d_ws;
        unsigned* totals  = blkhist + (size_t)B * NBLK;
        unsigned* offsets = totals + B;
        uint4*    buckets = (uint4*)((char*)d_ws + buckets_byte);
        float4*   pack    = (float4*)((char*)d_ws + pack_byte);

        pack_kernel<<<(N + 255) / 256, 256, 0, stream>>>(
            node_levels, node_q, pack, N);
        hist_kernel<<<NBLK, HTPB, B * 4, stream>>>(dst, blkhist, E, B, span);
        scan_blocks_kernel<<<B, NBLK, 0, stream>>>(blkhist, totals);
        scan_totals_kernel<<<1, 1024, 0, stream>>>(totals, offsets, B);
        scatter_sort_kernel<<<NBLK, TPB, 0, stream>>>(
            pack, edge_rel_q, edge_w, src, dst,
            blkhist, offsets, buckets, E, B, span);
        gather_sort_kernel<<<B, GTPB, 0, stream>>>(
            node_levels, node_q, offsets, buckets,
            (float4*)d_out, (float*)d_out + 4 * (long long)N, N);
    } else {
        // R3 fallback
        const int tpb = 256;
        size_t cnt_elems  = ((size_t)N + 3) & ~(size_t)3;
        size_t side_elems = 6 * (size_t)N;
        size_t head_bytes = (cnt_elems + side_elems) * 4;
        int cap = 0;
        for (int c : {128, 64}) {
            if (head_bytes + (size_t)N * c * 4 <= ws_size) { cap = c; break; }
        }
        int*   cnt    = (int*)d_ws;
        float* side   = (float*)d_ws + cnt_elems;
        int*   bucket = (int*)d_ws + cnt_elems + side_elems;
        hipMemsetAsync(d_ws, 0, head_bytes, stream);
        scatter_kernel<<<(E + tpb - 1) / tpb, tpb, 0, stream>>>(
            dst, cnt, bucket, cap, node_levels, node_q, edge_rel_q, edge_w, src, side, E);
        int waves  = (N + 1) / 2;
        int blocks = (waves * 64 + tpb - 1) / tpb;
        gather_kernel<<<blocks, tpb, 0, stream>>>(
            node_levels, node_q, edge_rel_q, edge_w, src, cnt, bucket, cap, side,
            (float4*)d_out, (float*)d_out + 4 * (long long)N, N);
    }
}